// Round 5
// baseline (1194.625 us; speedup 1.0000x reference)
//
#include <hip/hip_runtime.h>
#include <hip/hip_bf16.h>

#define DEVFN static __device__ __forceinline__

constexpr int N_ = 128, S_ = 64, T_ = N_ * S_;
constexpr int E_ = 256, H_ = 512, NH_ = 8, DH_ = 32, L_ = 4;
constexpr int V_ = 33279, VPAD_ = 33280, NVT_ = VPAD_ / 128;  // 260 v-tiles of 128

typedef __attribute__((ext_vector_type(8))) short bf16x8;
typedef __attribute__((ext_vector_type(4))) float f32x4;
typedef unsigned short ushort_t;

DEVFN ushort_t f2bf(float f) {
  unsigned int u = __float_as_uint(f);
  unsigned int r = (u + 0x7fffu + ((u >> 16) & 1u)) >> 16;
  return (ushort_t)r;
}
DEVFN float bf2f(ushort_t u) { return __uint_as_float(((unsigned)u) << 16); }

DEVFN float geluf(float x) {
  return 0.5f * x * (1.f + erff(x * 0.70710678118654752440f));
}

DEVFN float wave_sum(float v) {
  #pragma unroll
  for (int off = 32; off >= 1; off >>= 1) v += __shfl_xor(v, off, 64);
  return v;
}

// row-sum over the l15 dimension (16 lanes): offsets 1,2,4,8
DEVFN float l15_sum(float v) {
  v += __shfl_xor(v, 1, 64);
  v += __shfl_xor(v, 2, 64);
  v += __shfl_xor(v, 4, 64);
  v += __shfl_xor(v, 8, 64);
  return v;
}

// ---------------- embedding + LN: one wave per token row ----------------
__global__ __launch_bounds__(256) void k_embed_ln(
    const int* __restrict__ label, const int* __restrict__ mask,
    const float* __restrict__ emb, const float* __restrict__ pos,
    const float* __restrict__ g, const float* __restrict__ b,
    float* __restrict__ x, ushort_t* __restrict__ xb) {
  int wv = threadIdx.x >> 6, lane = threadIdx.x & 63;
  int t = blockIdx.x * 4 + wv;
  int s = t & (S_ - 1);
  int id = (mask[t] == 1) ? V_ : label[t];
  int c = lane * 4;
  float4 v = *(const float4*)&emb[(size_t)id * E_ + c];
  float4 p = *(const float4*)&pos[s * E_ + c];
  v.x += p.x; v.y += p.y; v.z += p.z; v.w += p.w;
  float mean = wave_sum(v.x + v.y + v.z + v.w) * (1.f / E_);
  float4 d = {v.x - mean, v.y - mean, v.z - mean, v.w - mean};
  float var = wave_sum(d.x * d.x + d.y * d.y + d.z * d.z + d.w * d.w) * (1.f / E_);
  float rstd = 1.f / sqrtf(var + 1e-5f);
  float4 g4 = *(const float4*)&g[c];
  float4 b4 = *(const float4*)&b[c];
  float4 y = {d.x * rstd * g4.x + b4.x, d.y * rstd * g4.y + b4.y,
              d.z * rstd * g4.z + b4.z, d.w * rstd * g4.w + b4.w};
  *(float4*)&x[(size_t)t * E_ + c] = y;
  ushort4 yb = {f2bf(y.x), f2bf(y.y), f2bf(y.z), f2bf(y.w)};
  *(ushort4*)&xb[(size_t)t * E_ + c] = yb;
}

// ---------------- bias concat ----------------
__global__ __launch_bounds__(256) void k_bcat(
    const float* __restrict__ bq, const float* __restrict__ bk,
    const float* __restrict__ bv, float* __restrict__ bqkv) {
  int l = blockIdx.x, i = threadIdx.x;
  bqkv[l * 768 + i]       = bq[l * 256 + i];
  bqkv[l * 768 + 256 + i] = bk[l * 256 + i];
  bqkv[l * 768 + 512 + i] = bv[l * 256 + i];
}

// ---------------- transpose+convert: src[L][K][J] f32 -> dst[L][J][K] bf16 -------
__global__ __launch_bounds__(256) void k_wt(const float* __restrict__ src,
                                            ushort_t* __restrict__ dst,
                                            int K, int J, int dstLayerStride) {
  __shared__ float tile[32][33];
  int j0 = blockIdx.x * 32, k0 = blockIdx.y * 32, l = blockIdx.z;
  src += (size_t)l * K * J;
  dst += (size_t)l * dstLayerStride;
  int tx = threadIdx.x & 31, ty = threadIdx.x >> 5;
  #pragma unroll
  for (int rr = 0; rr < 4; rr++) {
    int kk = ty * 4 + rr;
    tile[kk][tx] = src[(size_t)(k0 + kk) * J + j0 + tx];
  }
  __syncthreads();
  #pragma unroll
  for (int rr = 0; rr < 4; rr++) {
    int jj = ty * 4 + rr;
    dst[(size_t)(j0 + jj) * K + k0 + tx] = f2bf(tile[tx][jj]);
  }
}

// ---------------- combined E x E transposes (Wq/Wk/Wv/Wo x L + dW1) --------------
__global__ __launch_bounds__(256) void k_wtE(
    const float* __restrict__ Wq, const float* __restrict__ Wk,
    const float* __restrict__ Wv, const float* __restrict__ Wo,
    const float* __restrict__ dW1, ushort_t* __restrict__ wqkvT,
    ushort_t* __restrict__ woT, ushort_t* __restrict__ dw1T) {
  __shared__ float tile[32][33];
  int z = blockIdx.z;
  const float* src;
  ushort_t* dst;
  if (z == 4 * L_) {
    src = dW1; dst = dw1T;
  } else {
    int w = z >> 2, l = z & 3;
    const float* ws = (w == 0) ? Wq : (w == 1) ? Wk : (w == 2) ? Wv : Wo;
    src = ws + (size_t)l * E_ * E_;
    dst = (w < 3) ? (wqkvT + (size_t)l * 768 * E_ + (size_t)w * 256 * E_)
                  : (woT + (size_t)l * E_ * E_);
  }
  int j0 = blockIdx.x * 32, k0 = blockIdx.y * 32;
  int tx = threadIdx.x & 31, ty = threadIdx.x >> 5;
  #pragma unroll
  for (int rr = 0; rr < 4; rr++) {
    int kk = ty * 4 + rr;
    tile[kk][tx] = src[(size_t)(k0 + kk) * E_ + j0 + tx];
  }
  __syncthreads();
  #pragma unroll
  for (int rr = 0; rr < 4; rr++) {
    int jj = ty * 4 + rr;
    dst[(size_t)(j0 + jj) * E_ + k0 + tx] = f2bf(tile[tx][jj]);
  }
}

// ---------------- MFMA GEMM: C[T][Nout] = Xb[T][K] @ WT[Nout][K]^T + bias --------
template <int K, int OUT_BF16, int GELU_>
__global__ __launch_bounds__(256) void k_mm(
    const ushort_t* __restrict__ Xb, const ushort_t* __restrict__ WT,
    const float* __restrict__ bias, void* __restrict__ C, int Nout) {
  constexpr int STR = K + 8;
  __shared__ ushort_t xs[64 * STR];
  int tid = threadIdx.x, lane = tid & 63, wv = tid >> 6;
  int t0 = blockIdx.x * 64, j0 = blockIdx.y * 64;
  const ushort_t* xsrc = Xb + (size_t)t0 * K;
  for (int i = tid; i < 64 * (K / 8); i += 256) {
    int r = i / (K / 8), c = (i % (K / 8)) * 8;
    *(uint4*)&xs[r * STR + c] = *(const uint4*)&xsrc[(size_t)r * K + c];
  }
  __syncthreads();
  int l15 = lane & 15, l4 = lane >> 4;
  f32x4 acc[4] = {};
  const ushort_t* xrow = &xs[(wv * 16 + l15) * STR + l4 * 8];
  const ushort_t* wrow = WT + (size_t)j0 * K + l4 * 8;
  #pragma unroll
  for (int kb = 0; kb < K / 32; kb++) {
    bf16x8 a = *(const bf16x8*)(xrow + kb * 32);
    #pragma unroll
    for (int st = 0; st < 4; st++) {
      bf16x8 bfr = *(const bf16x8*)(wrow + (size_t)(st * 16 + l15) * K + kb * 32);
      acc[st] = __builtin_amdgcn_mfma_f32_16x16x32_bf16(a, bfr, acc[st], 0, 0, 0);
    }
  }
  #pragma unroll
  for (int st = 0; st < 4; st++) {
    int j = j0 + st * 16 + l15;
    float bv_ = bias[j];
    #pragma unroll
    for (int r = 0; r < 4; r++) {
      float val = acc[st][r] + bv_;
      if (GELU_) val = geluf(val);
      int t = t0 + wv * 16 + l4 * 4 + r;
      if (OUT_BF16)
        ((ushort_t*)C)[(size_t)t * Nout + j] = f2bf(val);
      else
        ((float*)C)[(size_t)t * Nout + j] = val;
    }
  }
}

// ---------------- fused attention + Wo + add-LN1: one block per sequence n -------
__global__ __launch_bounds__(256) void k_awl(
    const ushort_t* __restrict__ qkv, const ushort_t* __restrict__ woT_l,
    const float* __restrict__ bo_l, const float* __restrict__ xres,
    const float* __restrict__ g, const float* __restrict__ bet,
    float* __restrict__ y, ushort_t* __restrict__ yb) {
  __shared__ __align__(16) ushort_t vt_[NH_ * 32 * 72];  // V^T per head [h][d][t]
  __shared__ __align__(16) ushort_t ps[64 * 72];         // P [s][t] (wave-local rows)
  __shared__ __align__(16) ushort_t ol[64 * 264];        // O [s][e] bf16
  int n = blockIdx.x;
  int tid = threadIdx.x, lane = tid & 63, wv = tid >> 6;
  int l15 = lane & 15, l4 = lane >> 4;
  const ushort_t* qb = qkv + (size_t)n * S_ * 768;
  // stage V^T for all heads (coalesced over c = h*32+d)
  for (int i = tid; i < 64 * 256; i += 256) {
    int t = i >> 8, c = i & 255;
    vt_[c * 72 + t] = qb[(size_t)t * 768 + 512 + c];
  }
  __syncthreads();
  int srow = wv * 16 + l15;
  const float scale = 0.17677669529663687f;  // 1/sqrt(32)
  for (int h = 0; h < NH_; h++) {
    const ushort_t* qh = qb + h * DH_;
    bf16x8 aq = *(const bf16x8*)&qh[(size_t)srow * 768 + l4 * 8];
    f32x4 sc[4];
    #pragma unroll
    for (int st = 0; st < 4; st++) {
      bf16x8 bk_ = *(const bf16x8*)&qh[(size_t)(st * 16 + l15) * 768 + 256 + l4 * 8];
      f32x4 z = {};
      sc[st] = __builtin_amdgcn_mfma_f32_16x16x32_bf16(aq, bk_, z, 0, 0, 0);
    }
    #pragma unroll
    for (int st = 0; st < 4; st++)
      #pragma unroll
      for (int r = 0; r < 4; r++) sc[st][r] *= scale;
    #pragma unroll
    for (int r = 0; r < 4; r++) {
      float m = fmaxf(fmaxf(sc[0][r], sc[1][r]), fmaxf(sc[2][r], sc[3][r]));
      m = fmaxf(m, __shfl_xor(m, 1, 64));
      m = fmaxf(m, __shfl_xor(m, 2, 64));
      m = fmaxf(m, __shfl_xor(m, 4, 64));
      m = fmaxf(m, __shfl_xor(m, 8, 64));
      float p0 = __expf(sc[0][r] - m), p1 = __expf(sc[1][r] - m);
      float p2 = __expf(sc[2][r] - m), p3 = __expf(sc[3][r] - m);
      float sum = p0 + p1 + p2 + p3;
      sum += __shfl_xor(sum, 1, 64);
      sum += __shfl_xor(sum, 2, 64);
      sum += __shfl_xor(sum, 4, 64);
      sum += __shfl_xor(sum, 8, 64);
      float inv = 1.f / sum;
      int prow = (wv * 16 + l4 * 4 + r) * 72;
      ps[prow + 0 * 16 + l15] = f2bf(p0 * inv);
      ps[prow + 1 * 16 + l15] = f2bf(p1 * inv);
      ps[prow + 2 * 16 + l15] = f2bf(p2 * inv);
      ps[prow + 3 * 16 + l15] = f2bf(p3 * inv);
    }
    f32x4 oc[2] = {};
    #pragma unroll
    for (int kb = 0; kb < 2; kb++) {
      bf16x8 ap = *(const bf16x8*)&ps[srow * 72 + kb * 32 + l4 * 8];
      #pragma unroll
      for (int st2 = 0; st2 < 2; st2++) {
        bf16x8 bv_ = *(const bf16x8*)&vt_[(h * 32 + st2 * 16 + l15) * 72 + kb * 32 + l4 * 8];
        oc[st2] = __builtin_amdgcn_mfma_f32_16x16x32_bf16(ap, bv_, oc[st2], 0, 0, 0);
      }
    }
    #pragma unroll
    for (int st2 = 0; st2 < 2; st2++)
      #pragma unroll
      for (int r = 0; r < 4; r++)
        ol[(wv * 16 + l4 * 4 + r) * 264 + h * 32 + st2 * 16 + l15] = f2bf(oc[st2][r]);
  }
  // Wo: 16 rows x 256 cols per wave, A from ol (wave-local rows), B = woT
  f32x4 acc[4][4] = {};
  #pragma unroll
  for (int kb = 0; kb < 8; kb++) {
    bf16x8 a = *(const bf16x8*)&ol[(wv * 16 + l15) * 264 + kb * 32 + l4 * 8];
    #pragma unroll
    for (int jt = 0; jt < 4; jt++)
      #pragma unroll
      for (int st = 0; st < 4; st++) {
        bf16x8 b = *(const bf16x8*)&woT_l[(size_t)(jt * 64 + st * 16 + l15) * E_ + kb * 32 + l4 * 8];
        acc[jt][st] = __builtin_amdgcn_mfma_f32_16x16x32_bf16(a, b, acc[jt][st], 0, 0, 0);
      }
  }
  // epilogue: val = acc + bo + residual; LN over 256 cols; write x1 (f32) + x1b
  int t0 = n * 64;
  #pragma unroll
  for (int jt = 0; jt < 4; jt++)
    #pragma unroll
    for (int st = 0; st < 4; st++) {
      int j = jt * 64 + st * 16 + l15;
      float bv_ = bo_l[j];
      #pragma unroll
      for (int r = 0; r < 4; r++) {
        int t = t0 + wv * 16 + l4 * 4 + r;
        acc[jt][st][r] += bv_ + xres[(size_t)t * E_ + j];
      }
    }
  float rsum[4] = {0.f, 0.f, 0.f, 0.f};
  #pragma unroll
  for (int jt = 0; jt < 4; jt++)
    #pragma unroll
    for (int st = 0; st < 4; st++)
      #pragma unroll
      for (int r = 0; r < 4; r++) rsum[r] += acc[jt][st][r];
  float mean[4], rstd[4];
  #pragma unroll
  for (int r = 0; r < 4; r++) mean[r] = l15_sum(rsum[r]) * (1.f / E_);
  float rvar[4] = {0.f, 0.f, 0.f, 0.f};
  #pragma unroll
  for (int jt = 0; jt < 4; jt++)
    #pragma unroll
    for (int st = 0; st < 4; st++)
      #pragma unroll
      for (int r = 0; r < 4; r++) {
        float d = acc[jt][st][r] - mean[r];
        rvar[r] += d * d;
      }
  #pragma unroll
  for (int r = 0; r < 4; r++)
    rstd[r] = 1.f / sqrtf(l15_sum(rvar[r]) * (1.f / E_) + 1e-5f);
  #pragma unroll
  for (int jt = 0; jt < 4; jt++)
    #pragma unroll
    for (int st = 0; st < 4; st++) {
      int j = jt * 64 + st * 16 + l15;
      float gj = g[j], bj = bet[j];
      #pragma unroll
      for (int r = 0; r < 4; r++) {
        int t = t0 + wv * 16 + l4 * 4 + r;
        float o = (acc[jt][st][r] - mean[r]) * rstd[r] * gj + bj;
        y[(size_t)t * E_ + j] = o;
        yb[(size_t)t * E_ + j] = f2bf(o);
      }
    }
}

// ---------------- fused GEMM + (gelu) + (residual) + LN: 32 rows/block ----------
template <int K, int GELU_PRE, int HAS_RES, int OUT_F32>
__global__ __launch_bounds__(128) void k_mm_ln(
    const ushort_t* __restrict__ Xb, const ushort_t* __restrict__ WT,
    const float* __restrict__ bias, const float* __restrict__ res,
    const float* __restrict__ g, const float* __restrict__ bet,
    float* __restrict__ y, ushort_t* __restrict__ yb) {
  constexpr int STR = K + 8;
  __shared__ ushort_t xs[32 * STR];
  int tid = threadIdx.x, lane = tid & 63, wv = tid >> 6;  // wv in {0,1}
  int t0 = blockIdx.x * 32;
  const ushort_t* xsrc = Xb + (size_t)t0 * K;
  for (int i = tid; i < 32 * (K / 8); i += 128) {
    int r = i / (K / 8), c = (i % (K / 8)) * 8;
    *(uint4*)&xs[r * STR + c] = *(const uint4*)&xsrc[(size_t)r * K + c];
  }
  __syncthreads();
  int l15 = lane & 15, l4 = lane >> 4;
  f32x4 acc[4][4] = {};
  const ushort_t* xrow = &xs[(wv * 16 + l15) * STR + l4 * 8];
  #pragma unroll
  for (int kb = 0; kb < K / 32; kb++) {
    bf16x8 a = *(const bf16x8*)(xrow + kb * 32);
    #pragma unroll
    for (int jt = 0; jt < 4; jt++)
      #pragma unroll
      for (int st = 0; st < 4; st++) {
        bf16x8 b = *(const bf16x8*)(WT + (size_t)(jt * 64 + st * 16 + l15) * K + kb * 32 + l4 * 8);
        acc[jt][st] = __builtin_amdgcn_mfma_f32_16x16x32_bf16(a, b, acc[jt][st], 0, 0, 0);
      }
  }
  #pragma unroll
  for (int jt = 0; jt < 4; jt++)
    #pragma unroll
    for (int st = 0; st < 4; st++) {
      int j = jt * 64 + st * 16 + l15;
      float bv_ = bias[j];
      #pragma unroll
      for (int r = 0; r < 4; r++) {
        int t = t0 + wv * 16 + l4 * 4 + r;
        float v = acc[jt][st][r] + bv_;
        if (GELU_PRE) v = geluf(v);
        if (HAS_RES) v += res[(size_t)t * E_ + j];
        acc[jt][st][r] = v;
      }
    }
  float rsum[4] = {0.f, 0.f, 0.f, 0.f};
  #pragma unroll
  for (int jt = 0; jt < 4; jt++)
    #pragma unroll
    for (int st = 0; st < 4; st++)
      #pragma unroll
      for (int r = 0; r < 4; r++) rsum[r] += acc[jt][st][r];
  float mean[4], rstd[4];
  #pragma unroll
  for (int r = 0; r < 4; r++) mean[r] = l15_sum(rsum[r]) * (1.f / E_);
  float rvar[4] = {0.f, 0.f, 0.f, 0.f};
  #pragma unroll
  for (int jt = 0; jt < 4; jt++)
    #pragma unroll
    for (int st = 0; st < 4; st++)
      #pragma unroll
      for (int r = 0; r < 4; r++) {
        float d = acc[jt][st][r] - mean[r];
        rvar[r] += d * d;
      }
  #pragma unroll
  for (int r = 0; r < 4; r++)
    rstd[r] = 1.f / sqrtf(l15_sum(rvar[r]) * (1.f / E_) + 1e-5f);
  #pragma unroll
  for (int jt = 0; jt < 4; jt++)
    #pragma unroll
    for (int st = 0; st < 4; st++) {
      int j = jt * 64 + st * 16 + l15;
      float gj = g[j], bj = bet[j];
      #pragma unroll
      for (int r = 0; r < 4; r++) {
        int t = t0 + wv * 16 + l4 * 4 + r;
        float o = (acc[jt][st][r] - mean[r]) * rstd[r] * gj + bj;
        if (OUT_F32) y[(size_t)t * E_ + j] = o;
        yb[(size_t)t * E_ + j] = f2bf(o);
      }
    }
}

// ---------------- dW2 [E][V] f32 -> wt [VPAD][E] bf16 ----------------
__global__ __launch_bounds__(256) void k_w2t(const float* __restrict__ w,
                                             ushort_t* __restrict__ wt) {
  __shared__ float tile[32 * 33];
  int tx = threadIdx.x & 31, ty = threadIdx.x >> 5;
  int v0 = blockIdx.x * 32, k0 = blockIdx.y * 32;
  #pragma unroll
  for (int rr = 0; rr < 4; rr++) {
    int kk = ty * 4 + rr;
    int vv = v0 + tx;
    tile[kk * 33 + tx] = (vv < V_) ? w[(size_t)(k0 + kk) * V_ + vv] : 0.f;
  }
  __syncthreads();
  #pragma unroll
  for (int rr = 0; rr < 4; rr++) {
    int vv = ty * 4 + rr;
    wt[(size_t)(v0 + vv) * E_ + k0 + tx] = f2bf(tile[tx * 33 + vv]);
  }
}

// ---------------- vocab GEMM (128v x 64s tile) + fused softmax partials ----------
__global__ __launch_bounds__(256) void k_vocab(
    const ushort_t* __restrict__ hbf, const ushort_t* __restrict__ wt,
    const float* __restrict__ db2, float* __restrict__ out,
    float* __restrict__ pmax, float* __restrict__ psum) {
  __shared__ ushort_t hs[64 * 264];
  __shared__ float redm[4][64];
  __shared__ float reds[4][64];
  int n = blockIdx.x, vt = blockIdx.y;
  int tid = threadIdx.x, lane = tid & 63, wv = tid >> 6;
  const ushort_t* hsrc = hbf + (size_t)n * S_ * E_;
  for (int i = tid; i < (S_ * E_) / 8; i += 256) {
    int s = i >> 5, kc = (i & 31) * 8;
    *(uint4*)&hs[s * 264 + kc] = *(const uint4*)&hsrc[s * E_ + kc];
  }
  __syncthreads();
  int l15 = lane & 15, l4 = lane >> 4;
  const ushort_t* Ap0 = wt + (size_t)(vt * 128 + wv * 16 + l15) * E_ + l4 * 8;
  const ushort_t* Ap1 = Ap0 + (size_t)64 * E_;
  f32x4 acc[2][4] = {};
  #pragma unroll
  for (int kb = 0; kb < 8; kb++) {
    bf16x8 a0 = *(const bf16x8*)(Ap0 + kb * 32);
    bf16x8 a1 = *(const bf16x8*)(Ap1 + kb * 32);
    #pragma unroll
    for (int st = 0; st < 4; st++) {
      bf16x8 bfr = *(const bf16x8*)&hs[(st * 16 + l15) * 264 + kb * 32 + l4 * 8];
      acc[0][st] = __builtin_amdgcn_mfma_f32_16x16x32_bf16(a0, bfr, acc[0][st], 0, 0, 0);
      acc[1][st] = __builtin_amdgcn_mfma_f32_16x16x32_bf16(a1, bfr, acc[1][st], 0, 0, 0);
    }
  }
  float vals[2][4][4];
  #pragma unroll
  for (int mt = 0; mt < 2; mt++) {
    #pragma unroll
    for (int j = 0; j < 4; j++) {
      int v = vt * 128 + wv * 16 + mt * 64 + l4 * 4 + j;
      bool valid = v < V_;
      float bias = valid ? db2[v] : 0.f;
      size_t ob = ((size_t)n * V_ + v) * S_;
      #pragma unroll
      for (int st = 0; st < 4; st++) {
        float val = valid ? (acc[mt][st][j] + bias) : -INFINITY;
        vals[mt][st][j] = val;
        if (valid) __builtin_nontemporal_store(val, &out[ob + st * 16 + l15]);
      }
    }
  }
  float lm[4];
  #pragma unroll
  for (int st = 0; st < 4; st++) {
    float m = -INFINITY;
    #pragma unroll
    for (int mt = 0; mt < 2; mt++)
      #pragma unroll
      for (int j = 0; j < 4; j++) m = fmaxf(m, vals[mt][st][j]);
    m = fmaxf(m, __shfl_xor(m, 16, 64));
    m = fmaxf(m, __shfl_xor(m, 32, 64));
    lm[st] = m;
  }
  if (l4 == 0) {
    #pragma unroll
    for (int st = 0; st < 4; st++) redm[wv][st * 16 + l15] = lm[st];
  }
  __syncthreads();
  float bm[4], ls[4];
  #pragma unroll
  for (int st = 0; st < 4; st++) {
    int s = st * 16 + l15;
    bm[st] = fmaxf(fmaxf(redm[0][s], redm[1][s]), fmaxf(redm[2][s], redm[3][s]));
    float sum = 0.f;
    #pragma unroll
    for (int mt = 0; mt < 2; mt++)
      #pragma unroll
      for (int j = 0; j < 4; j++) sum += __expf(vals[mt][st][j] - bm[st]);
    sum += __shfl_xor(sum, 16, 64);
    sum += __shfl_xor(sum, 32, 64);
    ls[st] = sum;
  }
  if (l4 == 0) {
    #pragma unroll
    for (int st = 0; st < 4; st++) reds[wv][st * 16 + l15] = ls[st];
  }
  __syncthreads();
  if (wv == 0 && l4 == 0) {
    #pragma unroll
    for (int st = 0; st < 4; st++) {
      int s = st * 16 + l15;
      float bs = reds[0][s] + reds[1][s] + reds[2][s] + reds[3][s];
      size_t pi = ((size_t)n * NVT_ + vt) * S_ + s;
      pmax[pi] = bm[st];
      psum[pi] = bs;
    }
  }
}

// ---------------- loss finalize (512 threads) ----------------
__global__ __launch_bounds__(512) void k_lossf(
    const float* __restrict__ pmax, const float* __restrict__ psum,
    const float* __restrict__ out, const int* __restrict__ label,
    float* __restrict__ partial) {
  __shared__ float sm[512], ssum[512];
  int n = blockIdx.x, tid = threadIdx.x;
  int s = tid & 63, qq = tid >> 6;  // qq in [0,8)
  float m = -INFINITY, sum = 0.f;
  for (int vt = qq; vt < NVT_; vt += 8) {
    size_t pi = ((size_t)n * NVT_ + vt) * S_ + s;
    float m2 = pmax[pi], s2 = psum[pi];
    float nm = fmaxf(m, m2);
    sum = sum * __expf(m - nm) + s2 * __expf(m2 - nm);
    m = nm;
  }
  sm[tid] = m; ssum[tid] = sum;
  __syncthreads();
  if (qq == 0) {
    float M = sm[s], Sa = ssum[s];
    #pragma unroll
    for (int p = 1; p < 8; p++) {
      float m2 = sm[p * 64 + s], s2 = ssum[p * 64 + s];
      float nm = fmaxf(M, m2);
      Sa = Sa * __expf(M - nm) + s2 * __expf(m2 - nm);
      M = nm;
    }
    float lse = M + logf(Sa);
    int lab = label[n * S_ + s];
    float lx = out[((size_t)n * V_ + lab) * S_ + s];
    partial[n * S_ + s] = lse - lx;
  }
}

__global__ __launch_bounds__(256) void k_loss2(const float* __restrict__ partial,
                                               float* __restrict__ dst) {
  __shared__ float sbuf[4];
  int tid = threadIdx.x;
  float acc = 0.f;
  for (int i = tid; i < T_; i += 256) acc += partial[i];
  #pragma unroll
  for (int off = 32; off >= 1; off >>= 1) acc += __shfl_xor(acc, off, 64);
  int lane = tid & 63, wid = tid >> 6;
  if (lane == 0) sbuf[wid] = acc;
  __syncthreads();
  if (tid == 0) dst[0] = (sbuf[0] + sbuf[1] + sbuf[2] + sbuf[3]) / (float)T_;
}

extern "C" void kernel_launch(void* const* d_in, const int* in_sizes, int n_in,
                              void* d_out, int out_size, void* d_ws, size_t ws_size,
                              hipStream_t stream) {
  const int*   label = (const int*)d_in[0];
  const int*   mask  = (const int*)d_in[1];
  const float* emb   = (const float*)d_in[2];
  const float* pos   = (const float*)d_in[3];
  const float* emb_g = (const float*)d_in[4];
  const float* emb_b = (const float*)d_in[5];
  const float* Wq  = (const float*)d_in[6];
  const float* bq  = (const float*)d_in[7];
  const float* Wk  = (const float*)d_in[8];
  const float* bk  = (const float*)d_in[9];
  const float* Wv  = (const float*)d_in[10];
  const float* bv  = (const float*)d_in[11];
  const float* Wo  = (const float*)d_in[12];
  const float* bo  = (const float*)d_in[13];
  const float* n1g = (const float*)d_in[14];
  const float* n1b = (const float*)d_in[15];
  const float* W1  = (const float*)d_in[16];
  const float* b1  = (const float*)d_in[17];
  const float* W2  = (const float*)d_in[18];
  const float* b2  = (const float*)d_in[19];
  const float* n2g = (const float*)d_in[20];
  const float* n2b = (const float*)d_in[21];
  const float* dW1 = (const float*)d_in[22];
  const float* db1 = (const float*)d_in[23];
  const float* dng = (const float*)d_in[24];
  const float* dnb = (const float*)d_in[25];
  const float* dW2 = (const float*)d_in[26];
  const float* db2 = (const float*)d_in[27];
  float* out = (float*)d_out;
  (void)in_sizes; (void)n_in; (void)out_size; (void)ws_size;

  char* base = (char*)d_ws;
  size_t off = 0;
  auto alloc = [&](size_t bytes) {
    char* p = base + off;
    off += (bytes + 255) & ~(size_t)255;
    return p;
  };
  float*    x    = (float*)alloc((size_t)T_ * E_ * 4);
  ushort_t* xb   = (ushort_t*)alloc((size_t)T_ * E_ * 2);
  float*    x1   = (float*)alloc((size_t)T_ * E_ * 4);
  ushort_t* x1b  = (ushort_t*)alloc((size_t)T_ * E_ * 2);
  ushort_t* qkv  = (ushort_t*)alloc((size_t)T_ * 768 * 2);
  ushort_t* hbf  = (ushort_t*)alloc((size_t)T_ * E_ * 2);
  ushort_t* wqkvT = (ushort_t*)alloc((size_t)L_ * 768 * E_ * 2);
  ushort_t* woT   = (ushort_t*)alloc((size_t)L_ * E_ * E_ * 2);
  ushort_t* w1T   = (ushort_t*)alloc((size_t)L_ * H_ * E_ * 2);
  ushort_t* w2T   = (ushort_t*)alloc((size_t)L_ * E_ * H_ * 2);
  ushort_t* dw1T  = (ushort_t*)alloc((size_t)E_ * E_ * 2);
  ushort_t* wt    = (ushort_t*)alloc((size_t)VPAD_ * E_ * 2);
  float*    bqkv  = (float*)alloc((size_t)L_ * 768 * 4);
  float*    partial = (float*)alloc((size_t)T_ * 4);
  ushort_t* ffh = qkv;        // alias: qkv dead after k_awl each layer
  float* pmax = x;            // alias: x/x1 span dead by k_vocab (17 MB needed)
  float* psum = pmax + (size_t)N_ * NVT_ * S_;

  // ---- one-time weight prep (5 launches) ----
  k_bcat<<<L_, 256, 0, stream>>>(bq, bk, bv, bqkv);
  k_wtE<<<dim3(8, 8, 4 * L_ + 1), 256, 0, stream>>>(Wq, Wk, Wv, Wo, dW1, wqkvT, woT, dw1T);
  k_wt<<<dim3(16, 8, L_), 256, 0, stream>>>(W1, w1T, E_, H_, H_ * E_);
  k_wt<<<dim3(8, 16, L_), 256, 0, stream>>>(W2, w2T, H_, E_, E_ * H_);
  k_w2t<<<dim3(VPAD_ / 32, E_ / 32), 256, 0, stream>>>(dW2, wt);

  k_embed_ln<<<T_ / 4, 256, 0, stream>>>(label, mask, emb, pos, emb_g, emb_b, x, xb);

  for (int l = 0; l < L_; l++) {
    k_mm<E_, 1, 0><<<dim3(T_ / 64, 12), 256, 0, stream>>>(
        xb, wqkvT + (size_t)l * 768 * E_, bqkv + l * 768, qkv, 768);
    k_awl<<<N_, 256, 0, stream>>>(
        qkv, woT + (size_t)l * E_ * E_, bo + l * E_, x,
        n1g + l * E_, n1b + l * E_, x1, x1b);
    k_mm<E_, 1, 1><<<dim3(T_ / 64, 8), 256, 0, stream>>>(
        x1b, w1T + (size_t)l * H_ * E_, b1 + l * H_, ffh, H_);
    k_mm_ln<H_, 0, 1, 1><<<T_ / 32, 128, 0, stream>>>(
        ffh, w2T + (size_t)l * E_ * H_, b2 + l * E_, x1,
        n2g + l * E_, n2b + l * E_, x, xb);
  }

  // decoder head: gelu(x @ dW1 + db1) -> LN -> hbf (bf16)
  k_mm_ln<E_, 1, 0, 0><<<T_ / 32, 128, 0, stream>>>(
      xb, dw1T, db1, nullptr, dng, dnb, nullptr, hbf);

  // vocab projection + transposed store + fused softmax partials
  k_vocab<<<dim3(N_, NVT_), 256, 0, stream>>>(hbf, wt, db2, out, pmax, psum);

  // loss
  k_lossf<<<N_, 512, 0, stream>>>(pmax, psum, out, label, partial);
  k_loss2<<<1, 256, 0, stream>>>(partial, out + (size_t)N_ * V_ * S_);
}

// Round 6
// 922.951 us; speedup vs baseline: 1.2944x; 1.2944x over previous
//
#include <hip/hip_runtime.h>
#include <hip/hip_bf16.h>

#define DEVFN static __device__ __forceinline__

constexpr int N_ = 128, S_ = 64, T_ = N_ * S_;
constexpr int E_ = 256, H_ = 512, NH_ = 8, DH_ = 32, L_ = 4;
constexpr int V_ = 33279, VPAD_ = 33280, NVT_ = VPAD_ / 256;  // 130 v-tiles of 256

typedef __attribute__((ext_vector_type(8))) short bf16x8;
typedef __attribute__((ext_vector_type(4))) float f32x4;
typedef unsigned short ushort_t;

DEVFN ushort_t f2bf(float f) {
  unsigned int u = __float_as_uint(f);
  unsigned int r = (u + 0x7fffu + ((u >> 16) & 1u)) >> 16;
  return (ushort_t)r;
}
DEVFN float bf2f(ushort_t u) { return __uint_as_float(((unsigned)u) << 16); }

DEVFN float geluf(float x) {
  return 0.5f * x * (1.f + erff(x * 0.70710678118654752440f));
}

DEVFN float wave_sum(float v) {
  #pragma unroll
  for (int off = 32; off >= 1; off >>= 1) v += __shfl_xor(v, off, 64);
  return v;
}

// ---------------- embedding + LN: one wave per token row ----------------
__global__ __launch_bounds__(256) void k_embed_ln(
    const int* __restrict__ label, const int* __restrict__ mask,
    const float* __restrict__ emb, const float* __restrict__ pos,
    const float* __restrict__ g, const float* __restrict__ b,
    float* __restrict__ x, ushort_t* __restrict__ xb) {
  int wv = threadIdx.x >> 6, lane = threadIdx.x & 63;
  int t = blockIdx.x * 4 + wv;
  int s = t & (S_ - 1);
  int id = (mask[t] == 1) ? V_ : label[t];
  int c = lane * 4;
  float4 v = *(const float4*)&emb[(size_t)id * E_ + c];
  float4 p = *(const float4*)&pos[s * E_ + c];
  v.x += p.x; v.y += p.y; v.z += p.z; v.w += p.w;
  float mean = wave_sum(v.x + v.y + v.z + v.w) * (1.f / E_);
  float4 d = {v.x - mean, v.y - mean, v.z - mean, v.w - mean};
  float var = wave_sum(d.x * d.x + d.y * d.y + d.z * d.z + d.w * d.w) * (1.f / E_);
  float rstd = 1.f / sqrtf(var + 1e-5f);
  float4 g4 = *(const float4*)&g[c];
  float4 b4 = *(const float4*)&b[c];
  float4 y = {d.x * rstd * g4.x + b4.x, d.y * rstd * g4.y + b4.y,
              d.z * rstd * g4.z + b4.z, d.w * rstd * g4.w + b4.w};
  *(float4*)&x[(size_t)t * E_ + c] = y;
  ushort4 yb = {f2bf(y.x), f2bf(y.y), f2bf(y.z), f2bf(y.w)};
  *(ushort4*)&xb[(size_t)t * E_ + c] = yb;
}

// ---------------- residual add + LN: one wave per row ----------------
__global__ __launch_bounds__(256) void k_add_ln(
    const float* __restrict__ a, const float* __restrict__ bsrc,
    const float* __restrict__ g, const float* __restrict__ bet,
    float* __restrict__ y, ushort_t* __restrict__ yb) {
  int wv = threadIdx.x >> 6, lane = threadIdx.x & 63;
  int t = blockIdx.x * 4 + wv;
  int c = lane * 4;
  float4 v = *(const float4*)&a[(size_t)t * E_ + c];
  if (bsrc) {
    float4 u = *(const float4*)&bsrc[(size_t)t * E_ + c];
    v.x += u.x; v.y += u.y; v.z += u.z; v.w += u.w;
  }
  float mean = wave_sum(v.x + v.y + v.z + v.w) * (1.f / E_);
  float4 d = {v.x - mean, v.y - mean, v.z - mean, v.w - mean};
  float var = wave_sum(d.x * d.x + d.y * d.y + d.z * d.z + d.w * d.w) * (1.f / E_);
  float rstd = 1.f / sqrtf(var + 1e-5f);
  float4 g4 = *(const float4*)&g[c];
  float4 b4 = *(const float4*)&bet[c];
  float4 o = {d.x * rstd * g4.x + b4.x, d.y * rstd * g4.y + b4.y,
              d.z * rstd * g4.z + b4.z, d.w * rstd * g4.w + b4.w};
  if (y) *(float4*)&y[(size_t)t * E_ + c] = o;
  if (yb) {
    ushort4 ob = {f2bf(o.x), f2bf(o.y), f2bf(o.z), f2bf(o.w)};
    *(ushort4*)&yb[(size_t)t * E_ + c] = ob;
  }
}

// ---------------- bias concat ----------------
__global__ __launch_bounds__(256) void k_bcat(
    const float* __restrict__ bq, const float* __restrict__ bk,
    const float* __restrict__ bv, float* __restrict__ bqkv) {
  int l = blockIdx.x, i = threadIdx.x;
  bqkv[l * 768 + i]       = bq[l * 256 + i];
  bqkv[l * 768 + 256 + i] = bk[l * 256 + i];
  bqkv[l * 768 + 512 + i] = bv[l * 256 + i];
}

// ---------------- transpose+convert: src[L][K][J] f32 -> dst[L][J][K] bf16 -------
__global__ __launch_bounds__(256) void k_wt(const float* __restrict__ src,
                                            ushort_t* __restrict__ dst,
                                            int K, int J, int dstLayerStride) {
  __shared__ float tile[32][33];
  int j0 = blockIdx.x * 32, k0 = blockIdx.y * 32, l = blockIdx.z;
  src += (size_t)l * K * J;
  dst += (size_t)l * dstLayerStride;
  int tx = threadIdx.x & 31, ty = threadIdx.x >> 5;
  #pragma unroll
  for (int rr = 0; rr < 4; rr++) {
    int kk = ty * 4 + rr;
    tile[kk][tx] = src[(size_t)(k0 + kk) * J + j0 + tx];
  }
  __syncthreads();
  #pragma unroll
  for (int rr = 0; rr < 4; rr++) {
    int jj = ty * 4 + rr;
    dst[(size_t)(j0 + jj) * K + k0 + tx] = f2bf(tile[tx][jj]);
  }
}

// ---------------- combined E x E transposes (Wq/Wk/Wv/Wo x L + dW1) --------------
__global__ __launch_bounds__(256) void k_wtE(
    const float* __restrict__ Wq, const float* __restrict__ Wk,
    const float* __restrict__ Wv, const float* __restrict__ Wo,
    const float* __restrict__ dW1, ushort_t* __restrict__ wqkvT,
    ushort_t* __restrict__ woT, ushort_t* __restrict__ dw1T) {
  __shared__ float tile[32][33];
  int z = blockIdx.z;
  const float* src;
  ushort_t* dst;
  if (z == 4 * L_) {
    src = dW1; dst = dw1T;
  } else {
    int w = z >> 2, l = z & 3;
    const float* ws = (w == 0) ? Wq : (w == 1) ? Wk : (w == 2) ? Wv : Wo;
    src = ws + (size_t)l * E_ * E_;
    dst = (w < 3) ? (wqkvT + (size_t)l * 768 * E_ + (size_t)w * 256 * E_)
                  : (woT + (size_t)l * E_ * E_);
  }
  int j0 = blockIdx.x * 32, k0 = blockIdx.y * 32;
  int tx = threadIdx.x & 31, ty = threadIdx.x >> 5;
  #pragma unroll
  for (int rr = 0; rr < 4; rr++) {
    int kk = ty * 4 + rr;
    tile[kk][tx] = src[(size_t)(k0 + kk) * E_ + j0 + tx];
  }
  __syncthreads();
  #pragma unroll
  for (int rr = 0; rr < 4; rr++) {
    int jj = ty * 4 + rr;
    dst[(size_t)(j0 + jj) * E_ + k0 + tx] = f2bf(tile[tx][jj]);
  }
}

// ---------------- MFMA GEMM: C[T][Nout] = Xb[T][K] @ WT[Nout][K]^T + bias --------
template <int K, int OUT_BF16, int GELU_>
__global__ __launch_bounds__(256) void k_mm(
    const ushort_t* __restrict__ Xb, const ushort_t* __restrict__ WT,
    const float* __restrict__ bias, void* __restrict__ C, int Nout) {
  constexpr int STR = K + 8;
  __shared__ ushort_t xs[64 * STR];
  int tid = threadIdx.x, lane = tid & 63, wv = tid >> 6;
  int t0 = blockIdx.x * 64, j0 = blockIdx.y * 64;
  const ushort_t* xsrc = Xb + (size_t)t0 * K;
  for (int i = tid; i < 64 * (K / 8); i += 256) {
    int r = i / (K / 8), c = (i % (K / 8)) * 8;
    *(uint4*)&xs[r * STR + c] = *(const uint4*)&xsrc[(size_t)r * K + c];
  }
  __syncthreads();
  int l15 = lane & 15, l4 = lane >> 4;
  f32x4 acc[4] = {};
  const ushort_t* xrow = &xs[(wv * 16 + l15) * STR + l4 * 8];
  const ushort_t* wrow = WT + (size_t)j0 * K + l4 * 8;
  #pragma unroll
  for (int kb = 0; kb < K / 32; kb++) {
    bf16x8 a = *(const bf16x8*)(xrow + kb * 32);
    #pragma unroll
    for (int st = 0; st < 4; st++) {
      bf16x8 bfr = *(const bf16x8*)(wrow + (size_t)(st * 16 + l15) * K + kb * 32);
      acc[st] = __builtin_amdgcn_mfma_f32_16x16x32_bf16(a, bfr, acc[st], 0, 0, 0);
    }
  }
  #pragma unroll
  for (int st = 0; st < 4; st++) {
    int j = j0 + st * 16 + l15;
    float bv_ = bias[j];
    #pragma unroll
    for (int r = 0; r < 4; r++) {
      float val = acc[st][r] + bv_;
      if (GELU_) val = geluf(val);
      int t = t0 + wv * 16 + l4 * 4 + r;
      if (OUT_BF16)
        ((ushort_t*)C)[(size_t)t * Nout + j] = f2bf(val);
      else
        ((float*)C)[(size_t)t * Nout + j] = val;
    }
  }
}

// ---------------- MFMA attention: one block per (n, h) ----------------
__global__ __launch_bounds__(256) void k_attn(
    const ushort_t* __restrict__ qkv, ushort_t* __restrict__ o) {
  __shared__ __align__(16) ushort_t vt_[32 * 72];  // V^T [d][t]
  __shared__ __align__(16) ushort_t ps[64 * 72];   // P [s][t]
  int n = blockIdx.x >> 3, h = blockIdx.x & 7;
  int tid = threadIdx.x, lane = tid & 63, wv = tid >> 6;
  int l15 = lane & 15, l4 = lane >> 4;
  const ushort_t* qbase = qkv + (size_t)n * S_ * 768 + h * DH_;
  // stage V^T
  for (int i = tid; i < S_ * DH_; i += 256) {
    int t = i >> 5, d = i & 31;
    vt_[d * 72 + t] = qbase[(size_t)t * 768 + 512 + d];
  }
  // QK^T (K-dim = 32, one MFMA k-step)
  int srow = wv * 16 + l15;
  bf16x8 aq = *(const bf16x8*)&qbase[(size_t)srow * 768 + l4 * 8];
  f32x4 sc[4];
  #pragma unroll
  for (int st = 0; st < 4; st++) {
    bf16x8 bk_ = *(const bf16x8*)&qbase[(size_t)(st * 16 + l15) * 768 + 256 + l4 * 8];
    f32x4 z = {};
    sc[st] = __builtin_amdgcn_mfma_f32_16x16x32_bf16(aq, bk_, z, 0, 0, 0);
  }
  const float scale = 0.17677669529663687f;  // 1/sqrt(32)
  #pragma unroll
  for (int st = 0; st < 4; st++)
    #pragma unroll
    for (int r = 0; r < 4; r++) sc[st][r] *= scale;
  // softmax per s-row (s = wv*16 + l4*4 + r); t spread over (st, l15)
  #pragma unroll
  for (int r = 0; r < 4; r++) {
    float m = fmaxf(fmaxf(sc[0][r], sc[1][r]), fmaxf(sc[2][r], sc[3][r]));
    m = fmaxf(m, __shfl_xor(m, 1, 64));
    m = fmaxf(m, __shfl_xor(m, 2, 64));
    m = fmaxf(m, __shfl_xor(m, 4, 64));
    m = fmaxf(m, __shfl_xor(m, 8, 64));
    float p0 = __expf(sc[0][r] - m), p1 = __expf(sc[1][r] - m);
    float p2 = __expf(sc[2][r] - m), p3 = __expf(sc[3][r] - m);
    float sum = p0 + p1 + p2 + p3;
    sum += __shfl_xor(sum, 1, 64);
    sum += __shfl_xor(sum, 2, 64);
    sum += __shfl_xor(sum, 4, 64);
    sum += __shfl_xor(sum, 8, 64);
    float inv = 1.f / sum;
    int prow = (wv * 16 + l4 * 4 + r) * 72;
    ps[prow + 0 * 16 + l15] = f2bf(p0 * inv);
    ps[prow + 1 * 16 + l15] = f2bf(p1 * inv);
    ps[prow + 2 * 16 + l15] = f2bf(p2 * inv);
    ps[prow + 3 * 16 + l15] = f2bf(p3 * inv);
  }
  __syncthreads();
  // PV: O[s][d] = P[s][t] @ V[t][d], via A=P rows, B=V^T rows
  f32x4 oc[2] = {};
  #pragma unroll
  for (int kb = 0; kb < 2; kb++) {
    bf16x8 ap = *(const bf16x8*)&ps[srow * 72 + kb * 32 + l4 * 8];
    #pragma unroll
    for (int st2 = 0; st2 < 2; st2++) {
      bf16x8 bv_ = *(const bf16x8*)&vt_[(st2 * 16 + l15) * 72 + kb * 32 + l4 * 8];
      oc[st2] = __builtin_amdgcn_mfma_f32_16x16x32_bf16(ap, bv_, oc[st2], 0, 0, 0);
    }
  }
  ushort_t* ob = o + (size_t)n * S_ * E_ + h * DH_;
  #pragma unroll
  for (int st2 = 0; st2 < 2; st2++)
    #pragma unroll
    for (int r = 0; r < 4; r++)
      ob[(size_t)(wv * 16 + l4 * 4 + r) * E_ + st2 * 16 + l15] = f2bf(oc[st2][r]);
}

// ---------------- dW2 [E][V] f32 -> wt [VPAD][E] bf16 ----------------
__global__ __launch_bounds__(256) void k_w2t(const float* __restrict__ w,
                                             ushort_t* __restrict__ wt) {
  __shared__ float tile[32 * 33];
  int tx = threadIdx.x & 31, ty = threadIdx.x >> 5;
  int v0 = blockIdx.x * 32, k0 = blockIdx.y * 32;
  #pragma unroll
  for (int rr = 0; rr < 4; rr++) {
    int kk = ty * 4 + rr;
    int vv = v0 + tx;
    tile[kk * 33 + tx] = (vv < V_) ? w[(size_t)(k0 + kk) * V_ + vv] : 0.f;
  }
  __syncthreads();
  #pragma unroll
  for (int rr = 0; rr < 4; rr++) {
    int vv = ty * 4 + rr;
    wt[(size_t)(v0 + vv) * E_ + k0 + tx] = f2bf(tile[tx * 33 + vv]);
  }
}

// ---------------- vocab GEMM: 256v x 64s per block, two 128-v halves -------------
__global__ __launch_bounds__(256) void k_vocab(
    const ushort_t* __restrict__ hbf, const ushort_t* __restrict__ wt,
    const float* __restrict__ db2, float* __restrict__ out,
    float* __restrict__ pmax, float* __restrict__ psum) {
  __shared__ ushort_t hs[64 * 264];
  __shared__ float redm[4][64];
  __shared__ float reds[4][64];
  int n = blockIdx.x, vt = blockIdx.y;
  int tid = threadIdx.x, lane = tid & 63, wv = tid >> 6;
  const ushort_t* hsrc = hbf + (size_t)n * S_ * E_;
  for (int i = tid; i < (S_ * E_) / 8; i += 256) {
    int s = i >> 5, kc = (i & 31) * 8;
    *(uint4*)&hs[s * 264 + kc] = *(const uint4*)&hsrc[s * E_ + kc];
  }
  __syncthreads();
  int l15 = lane & 15, l4 = lane >> 4;
  float rm[4], rs[4];
  #pragma unroll
  for (int st = 0; st < 4; st++) { rm[st] = -INFINITY; rs[st] = 0.f; }
  #pragma unroll
  for (int h2 = 0; h2 < 2; h2++) {
    const ushort_t* Ap0 =
        wt + (size_t)(vt * 256 + h2 * 128 + wv * 16 + l15) * E_ + l4 * 8;
    const ushort_t* Ap1 = Ap0 + (size_t)64 * E_;
    f32x4 acc[2][4] = {};
    #pragma unroll
    for (int kb = 0; kb < 8; kb++) {
      bf16x8 a0 = *(const bf16x8*)(Ap0 + kb * 32);
      bf16x8 a1 = *(const bf16x8*)(Ap1 + kb * 32);
      #pragma unroll
      for (int st = 0; st < 4; st++) {
        bf16x8 bfr = *(const bf16x8*)&hs[(st * 16 + l15) * 264 + kb * 32 + l4 * 8];
        acc[0][st] = __builtin_amdgcn_mfma_f32_16x16x32_bf16(a0, bfr, acc[0][st], 0, 0, 0);
        acc[1][st] = __builtin_amdgcn_mfma_f32_16x16x32_bf16(a1, bfr, acc[1][st], 0, 0, 0);
      }
    }
    // vals[mt][st][j]: v = vt*256 + h2*128 + wv*16 + mt*64 + l4*4 + j, s = st*16+l15
    float vals[2][4][4];
    #pragma unroll
    for (int mt = 0; mt < 2; mt++) {
      #pragma unroll
      for (int j = 0; j < 4; j++) {
        int v = vt * 256 + h2 * 128 + wv * 16 + mt * 64 + l4 * 4 + j;
        bool valid = v < V_;
        float bias = valid ? db2[v] : 0.f;
        size_t ob = ((size_t)n * V_ + v) * S_;
        #pragma unroll
        for (int st = 0; st < 4; st++) {
          float val = valid ? (acc[mt][st][j] + bias) : -INFINITY;
          vals[mt][st][j] = val;
          if (valid) __builtin_nontemporal_store(val, &out[ob + st * 16 + l15]);
        }
      }
    }
    // per-s (max, sumexp) over this half's 128 v, merged online into (rm, rs)
    #pragma unroll
    for (int st = 0; st < 4; st++) {
      float m = -INFINITY;
      #pragma unroll
      for (int mt = 0; mt < 2; mt++)
        #pragma unroll
        for (int j = 0; j < 4; j++) m = fmaxf(m, vals[mt][st][j]);
      m = fmaxf(m, __shfl_xor(m, 16, 64));
      m = fmaxf(m, __shfl_xor(m, 32, 64));
      float sum = 0.f;
      #pragma unroll
      for (int mt = 0; mt < 2; mt++)
        #pragma unroll
        for (int j = 0; j < 4; j++) sum += __expf(vals[mt][st][j] - m);
      sum += __shfl_xor(sum, 16, 64);
      sum += __shfl_xor(sum, 32, 64);
      float nm = fmaxf(rm[st], m);
      rs[st] = rs[st] * __expf(rm[st] - nm) + sum * __expf(m - nm);
      rm[st] = nm;
    }
  }
  if (l4 == 0) {
    #pragma unroll
    for (int st = 0; st < 4; st++) {
      redm[wv][st * 16 + l15] = rm[st];
      reds[wv][st * 16 + l15] = rs[st];
    }
  }
  __syncthreads();
  if (wv == 0 && l4 == 0) {
    #pragma unroll
    for (int st = 0; st < 4; st++) {
      int s = st * 16 + l15;
      float M = fmaxf(fmaxf(redm[0][s], redm[1][s]), fmaxf(redm[2][s], redm[3][s]));
      float Sa = reds[0][s] * __expf(redm[0][s] - M) +
                 reds[1][s] * __expf(redm[1][s] - M) +
                 reds[2][s] * __expf(redm[2][s] - M) +
                 reds[3][s] * __expf(redm[3][s] - M);
      size_t pi = ((size_t)n * NVT_ + vt) * S_ + s;
      pmax[pi] = M;
      psum[pi] = Sa;
    }
  }
}

// ---------------- loss finalize (512 threads) ----------------
__global__ __launch_bounds__(512) void k_lossf(
    const float* __restrict__ pmax, const float* __restrict__ psum,
    const float* __restrict__ out, const int* __restrict__ label,
    float* __restrict__ partial) {
  __shared__ float sm[512], ssum[512];
  int n = blockIdx.x, tid = threadIdx.x;
  int s = tid & 63, qq = tid >> 6;  // qq in [0,8)
  float m = -INFINITY, sum = 0.f;
  for (int vt = qq; vt < NVT_; vt += 8) {
    size_t pi = ((size_t)n * NVT_ + vt) * S_ + s;
    float m2 = pmax[pi], s2 = psum[pi];
    float nm = fmaxf(m, m2);
    sum = sum * __expf(m - nm) + s2 * __expf(m2 - nm);
    m = nm;
  }
  sm[tid] = m; ssum[tid] = sum;
  __syncthreads();
  if (qq == 0) {
    float M = sm[s], Sa = ssum[s];
    #pragma unroll
    for (int p = 1; p < 8; p++) {
      float m2 = sm[p * 64 + s], s2 = ssum[p * 64 + s];
      float nm = fmaxf(M, m2);
      Sa = Sa * __expf(M - nm) + s2 * __expf(m2 - nm);
      M = nm;
    }
    float lse = M + logf(Sa);
    int lab = label[n * S_ + s];
    float lx = out[((size_t)n * V_ + lab) * S_ + s];
    partial[n * S_ + s] = lse - lx;
  }
}

__global__ __launch_bounds__(256) void k_loss2(const float* __restrict__ partial,
                                               float* __restrict__ dst) {
  __shared__ float sbuf[4];
  int tid = threadIdx.x;
  float acc = 0.f;
  for (int i = tid; i < T_; i += 256) acc += partial[i];
  #pragma unroll
  for (int off = 32; off >= 1; off >>= 1) acc += __shfl_xor(acc, off, 64);
  int lane = tid & 63, wid = tid >> 6;
  if (lane == 0) sbuf[wid] = acc;
  __syncthreads();
  if (tid == 0) dst[0] = (sbuf[0] + sbuf[1] + sbuf[2] + sbuf[3]) / (float)T_;
}

extern "C" void kernel_launch(void* const* d_in, const int* in_sizes, int n_in,
                              void* d_out, int out_size, void* d_ws, size_t ws_size,
                              hipStream_t stream) {
  const int*   label = (const int*)d_in[0];
  const int*   mask  = (const int*)d_in[1];
  const float* emb   = (const float*)d_in[2];
  const float* pos   = (const float*)d_in[3];
  const float* emb_g = (const float*)d_in[4];
  const float* emb_b = (const float*)d_in[5];
  const float* Wq  = (const float*)d_in[6];
  const float* bq  = (const float*)d_in[7];
  const float* Wk  = (const float*)d_in[8];
  const float* bk  = (const float*)d_in[9];
  const float* Wv  = (const float*)d_in[10];
  const float* bv  = (const float*)d_in[11];
  const float* Wo  = (const float*)d_in[12];
  const float* bo  = (const float*)d_in[13];
  const float* n1g = (const float*)d_in[14];
  const float* n1b = (const float*)d_in[15];
  const float* W1  = (const float*)d_in[16];
  const float* b1  = (const float*)d_in[17];
  const float* W2  = (const float*)d_in[18];
  const float* b2  = (const float*)d_in[19];
  const float* n2g = (const float*)d_in[20];
  const float* n2b = (const float*)d_in[21];
  const float* dW1 = (const float*)d_in[22];
  const float* db1 = (const float*)d_in[23];
  const float* dng = (const float*)d_in[24];
  const float* dnb = (const float*)d_in[25];
  const float* dW2 = (const float*)d_in[26];
  const float* db2 = (const float*)d_in[27];
  float* out = (float*)d_out;
  (void)in_sizes; (void)n_in; (void)out_size; (void)ws_size;

  char* base = (char*)d_ws;
  size_t off = 0;
  auto alloc = [&](size_t bytes) {
    char* p = base + off;
    off += (bytes + 255) & ~(size_t)255;
    return p;
  };
  float*    x    = (float*)alloc((size_t)T_ * E_ * 4);
  ushort_t* xb   = (ushort_t*)alloc((size_t)T_ * E_ * 2);
  float*    x1   = (float*)alloc((size_t)T_ * E_ * 4);
  ushort_t* x1b  = (ushort_t*)alloc((size_t)T_ * E_ * 2);
  ushort_t* qkv  = (ushort_t*)alloc((size_t)T_ * 768 * 2);
  ushort_t* obuf = (ushort_t*)alloc((size_t)T_ * E_ * 2);
  float*    ftmp = (float*)alloc((size_t)T_ * E_ * 4);
  ushort_t* wqkvT = (ushort_t*)alloc((size_t)L_ * 768 * E_ * 2);
  ushort_t* woT   = (ushort_t*)alloc((size_t)L_ * E_ * E_ * 2);
  ushort_t* w1T   = (ushort_t*)alloc((size_t)L_ * H_ * E_ * 2);
  ushort_t* w2T   = (ushort_t*)alloc((size_t)L_ * E_ * H_ * 2);
  ushort_t* dw1T  = (ushort_t*)alloc((size_t)E_ * E_ * 2);
  ushort_t* wt    = (ushort_t*)alloc((size_t)VPAD_ * E_ * 2);
  float*    bqkv  = (float*)alloc((size_t)L_ * 768 * 4);
  float*    partial = (float*)alloc((size_t)T_ * 4);
  ushort_t* ffh = qkv;        // alias: qkv dead after attn
  ushort_t* hbf = obuf;       // alias: obuf dead before decoder LN
  float* pmax = x;            // alias: x.. span dead by k_vocab (~8.6 MB needed)
  float* psum = pmax + (size_t)N_ * NVT_ * S_;

  // ---- one-time weight prep (5 launches) ----
  k_bcat<<<L_, 256, 0, stream>>>(bq, bk, bv, bqkv);
  k_wtE<<<dim3(8, 8, 4 * L_ + 1), 256, 0, stream>>>(Wq, Wk, Wv, Wo, dW1, wqkvT, woT, dw1T);
  k_wt<<<dim3(16, 8, L_), 256, 0, stream>>>(W1, w1T, E_, H_, H_ * E_);
  k_wt<<<dim3(8, 16, L_), 256, 0, stream>>>(W2, w2T, H_, E_, E_ * H_);
  k_w2t<<<dim3(VPAD_ / 32, E_ / 32), 256, 0, stream>>>(dW2, wt);

  k_embed_ln<<<T_ / 4, 256, 0, stream>>>(label, mask, emb, pos, emb_g, emb_b, x, xb);

  for (int l = 0; l < L_; l++) {
    k_mm<E_, 1, 0><<<dim3(T_ / 64, 12), 256, 0, stream>>>(
        xb, wqkvT + (size_t)l * 768 * E_, bqkv + l * 768, qkv, 768);
    k_attn<<<N_ * NH_, 256, 0, stream>>>(qkv, obuf);
    k_mm<E_, 0, 0><<<dim3(T_ / 64, 4), 256, 0, stream>>>(
        obuf, woT + (size_t)l * E_ * E_, bo + l * E_, ftmp, E_);
    k_add_ln<<<T_ / 4, 256, 0, stream>>>(x, ftmp, n1g + l * E_, n1b + l * E_, x1, x1b);
    k_mm<E_, 1, 1><<<dim3(T_ / 64, 8), 256, 0, stream>>>(
        x1b, w1T + (size_t)l * H_ * E_, b1 + l * H_, ffh, H_);
    k_mm<H_, 0, 0><<<dim3(T_ / 64, 4), 256, 0, stream>>>(
        ffh, w2T + (size_t)l * E_ * H_, b2 + l * E_, ftmp, E_);
    k_add_ln<<<T_ / 4, 256, 0, stream>>>(x1, ftmp, n2g + l * E_, n2b + l * E_, x, xb);
  }

  // decoder head
  k_mm<E_, 0, 1><<<dim3(T_ / 64, 4), 256, 0, stream>>>(xb, dw1T, db1, ftmp, E_);
  k_add_ln<<<T_ / 4, 256, 0, stream>>>(ftmp, nullptr, dng, dnb, nullptr, hbf);

  // vocab projection + transposed store + fused softmax partials
  k_vocab<<<dim3(N_, NVT_), 256, 0, stream>>>(hbf, wt, db2, out, pmax, psum);

  // loss
  k_lossf<<<N_, 512, 0, stream>>>(pmax, psum, out, label, partial);
  k_loss2<<<1, 256, 0, stream>>>(partial, out + (size_t)N_ * V_ * S_);
}

// Round 7
// 875.631 us; speedup vs baseline: 1.3643x; 1.0540x over previous
//
#include <hip/hip_runtime.h>
#include <hip/hip_bf16.h>

#define DEVFN static __device__ __forceinline__

constexpr int N_ = 128, S_ = 64, T_ = N_ * S_;
constexpr int E_ = 256, H_ = 512, NH_ = 8, DH_ = 32, L_ = 4;
constexpr int V_ = 33279, VPAD_ = 33280, NVT_ = VPAD_ / 256;  // 130 v-tiles of 256

typedef __attribute__((ext_vector_type(8))) short bf16x8;
typedef __attribute__((ext_vector_type(4))) float f32x4;
typedef unsigned short ushort_t;

DEVFN ushort_t f2bf(float f) {
  unsigned int u = __float_as_uint(f);
  unsigned int r = (u + 0x7fffu + ((u >> 16) & 1u)) >> 16;
  return (ushort_t)r;
}
DEVFN float bf2f(ushort_t u) { return __uint_as_float(((unsigned)u) << 16); }

DEVFN float geluf(float x) {
  return 0.5f * x * (1.f + erff(x * 0.70710678118654752440f));
}

DEVFN float wave_sum(float v) {
  #pragma unroll
  for (int off = 32; off >= 1; off >>= 1) v += __shfl_xor(v, off, 64);
  return v;
}

// sum across the 16-lane l15 group (keeps l4 groups separate)
DEVFN float l15_sum(float v) {
  v += __shfl_xor(v, 1, 64);
  v += __shfl_xor(v, 2, 64);
  v += __shfl_xor(v, 4, 64);
  v += __shfl_xor(v, 8, 64);
  return v;
}

// ---------------- embedding + LN: one wave per token row ----------------
__global__ __launch_bounds__(256) void k_embed_ln(
    const int* __restrict__ label, const int* __restrict__ mask,
    const float* __restrict__ emb, const float* __restrict__ pos,
    const float* __restrict__ g, const float* __restrict__ b,
    float* __restrict__ x, ushort_t* __restrict__ xb) {
  int wv = threadIdx.x >> 6, lane = threadIdx.x & 63;
  int t = blockIdx.x * 4 + wv;
  int s = t & (S_ - 1);
  int id = (mask[t] == 1) ? V_ : label[t];
  int c = lane * 4;
  float4 v = *(const float4*)&emb[(size_t)id * E_ + c];
  float4 p = *(const float4*)&pos[s * E_ + c];
  v.x += p.x; v.y += p.y; v.z += p.z; v.w += p.w;
  float mean = wave_sum(v.x + v.y + v.z + v.w) * (1.f / E_);
  float4 d = {v.x - mean, v.y - mean, v.z - mean, v.w - mean};
  float var = wave_sum(d.x * d.x + d.y * d.y + d.z * d.z + d.w * d.w) * (1.f / E_);
  float rstd = 1.f / sqrtf(var + 1e-5f);
  float4 g4 = *(const float4*)&g[c];
  float4 b4 = *(const float4*)&b[c];
  float4 y = {d.x * rstd * g4.x + b4.x, d.y * rstd * g4.y + b4.y,
              d.z * rstd * g4.z + b4.z, d.w * rstd * g4.w + b4.w};
  *(float4*)&x[(size_t)t * E_ + c] = y;
  ushort4 yb = {f2bf(y.x), f2bf(y.y), f2bf(y.z), f2bf(y.w)};
  *(ushort4*)&xb[(size_t)t * E_ + c] = yb;
}

// ---------------- bias concat ----------------
__global__ __launch_bounds__(256) void k_bcat(
    const float* __restrict__ bq, const float* __restrict__ bk,
    const float* __restrict__ bv, float* __restrict__ bqkv) {
  int l = blockIdx.x, i = threadIdx.x;
  bqkv[l * 768 + i]       = bq[l * 256 + i];
  bqkv[l * 768 + 256 + i] = bk[l * 256 + i];
  bqkv[l * 768 + 512 + i] = bv[l * 256 + i];
}

// ---------------- transpose+convert: src[L][K][J] f32 -> dst[L][J][K] bf16 -------
__global__ __launch_bounds__(256) void k_wt(const float* __restrict__ src,
                                            ushort_t* __restrict__ dst,
                                            int K, int J, int dstLayerStride) {
  __shared__ float tile[32][33];
  int j0 = blockIdx.x * 32, k0 = blockIdx.y * 32, l = blockIdx.z;
  src += (size_t)l * K * J;
  dst += (size_t)l * dstLayerStride;
  int tx = threadIdx.x & 31, ty = threadIdx.x >> 5;
  #pragma unroll
  for (int rr = 0; rr < 4; rr++) {
    int kk = ty * 4 + rr;
    tile[kk][tx] = src[(size_t)(k0 + kk) * J + j0 + tx];
  }
  __syncthreads();
  #pragma unroll
  for (int rr = 0; rr < 4; rr++) {
    int jj = ty * 4 + rr;
    dst[(size_t)(j0 + jj) * K + k0 + tx] = f2bf(tile[tx][jj]);
  }
}

// ---------------- combined E x E transposes (Wq/Wk/Wv/Wo x L + dW1) --------------
__global__ __launch_bounds__(256) void k_wtE(
    const float* __restrict__ Wq, const float* __restrict__ Wk,
    const float* __restrict__ Wv, const float* __restrict__ Wo,
    const float* __restrict__ dW1, ushort_t* __restrict__ wqkvT,
    ushort_t* __restrict__ woT, ushort_t* __restrict__ dw1T) {
  __shared__ float tile[32][33];
  int z = blockIdx.z;
  const float* src;
  ushort_t* dst;
  if (z == 4 * L_) {
    src = dW1; dst = dw1T;
  } else {
    int w = z >> 2, l = z & 3;
    const float* ws = (w == 0) ? Wq : (w == 1) ? Wk : (w == 2) ? Wv : Wo;
    src = ws + (size_t)l * E_ * E_;
    dst = (w < 3) ? (wqkvT + (size_t)l * 768 * E_ + (size_t)w * 256 * E_)
                  : (woT + (size_t)l * E_ * E_);
  }
  int j0 = blockIdx.x * 32, k0 = blockIdx.y * 32;
  int tx = threadIdx.x & 31, ty = threadIdx.x >> 5;
  #pragma unroll
  for (int rr = 0; rr < 4; rr++) {
    int kk = ty * 4 + rr;
    tile[kk][tx] = src[(size_t)(k0 + kk) * E_ + j0 + tx];
  }
  __syncthreads();
  #pragma unroll
  for (int rr = 0; rr < 4; rr++) {
    int jj = ty * 4 + rr;
    dst[(size_t)(j0 + jj) * E_ + k0 + tx] = f2bf(tile[tx][jj]);
  }
}

// ---------------- MFMA GEMM: C[T][Nout] = Xb[T][K] @ WT[Nout][K]^T + bias --------
template <int K, int OUT_BF16, int GELU_>
__global__ __launch_bounds__(256) void k_mm(
    const ushort_t* __restrict__ Xb, const ushort_t* __restrict__ WT,
    const float* __restrict__ bias, void* __restrict__ C, int Nout) {
  constexpr int STR = K + 8;
  __shared__ ushort_t xs[64 * STR];
  int tid = threadIdx.x, lane = tid & 63, wv = tid >> 6;
  int t0 = blockIdx.x * 64, j0 = blockIdx.y * 64;
  const ushort_t* xsrc = Xb + (size_t)t0 * K;
  for (int i = tid; i < 64 * (K / 8); i += 256) {
    int r = i / (K / 8), c = (i % (K / 8)) * 8;
    *(uint4*)&xs[r * STR + c] = *(const uint4*)&xsrc[(size_t)r * K + c];
  }
  __syncthreads();
  int l15 = lane & 15, l4 = lane >> 4;
  f32x4 acc[4] = {};
  const ushort_t* xrow = &xs[(wv * 16 + l15) * STR + l4 * 8];
  const ushort_t* wrow = WT + (size_t)j0 * K + l4 * 8;
  #pragma unroll
  for (int kb = 0; kb < K / 32; kb++) {
    bf16x8 a = *(const bf16x8*)(xrow + kb * 32);
    #pragma unroll
    for (int st = 0; st < 4; st++) {
      bf16x8 bfr = *(const bf16x8*)(wrow + (size_t)(st * 16 + l15) * K + kb * 32);
      acc[st] = __builtin_amdgcn_mfma_f32_16x16x32_bf16(a, bfr, acc[st], 0, 0, 0);
    }
  }
  #pragma unroll
  for (int st = 0; st < 4; st++) {
    int j = j0 + st * 16 + l15;
    float bv_ = bias[j];
    #pragma unroll
    for (int r = 0; r < 4; r++) {
      float val = acc[st][r] + bv_;
      if (GELU_) val = geluf(val);
      int t = t0 + wv * 16 + l4 * 4 + r;
      if (OUT_BF16)
        ((ushort_t*)C)[(size_t)t * Nout + j] = f2bf(val);
      else
        ((float*)C)[(size_t)t * Nout + j] = val;
    }
  }
}

// ------- fused GEMM (Nout=256) + [gelu] + [residual] + LN, 16 rows/block --------
// 4 waves: wave wv owns cols [wv*64, wv*64+64), all 16 rows. LN via LDS reduce.
template <int K, int GELU_PRE, int HAS_RES, int OUT_F32>
__global__ __launch_bounds__(256) void k_mm_ln2(
    const ushort_t* __restrict__ Xb, const ushort_t* __restrict__ WT,
    const float* __restrict__ bias, const float* __restrict__ res,
    const float* __restrict__ g, const float* __restrict__ bet,
    float* __restrict__ y, ushort_t* __restrict__ yb) {
  constexpr int STR = K + 8;
  __shared__ ushort_t xs[16 * STR];
  __shared__ float redA[4][16], redB[4][16];
  int tid = threadIdx.x, lane = tid & 63, wv = tid >> 6;
  int t0 = blockIdx.x * 16;
  const ushort_t* xsrc = Xb + (size_t)t0 * K;
  for (int i = tid; i < 16 * (K / 8); i += 256) {
    int r = i / (K / 8), c = (i % (K / 8)) * 8;
    *(uint4*)&xs[r * STR + c] = *(const uint4*)&xsrc[(size_t)r * K + c];
  }
  __syncthreads();
  int l15 = lane & 15, l4 = lane >> 4;
  f32x4 acc[4] = {};
  const ushort_t* xrow = &xs[l15 * STR + l4 * 8];
  const ushort_t* wrow = WT + (size_t)(wv * 64) * K + l4 * 8;
  #pragma unroll
  for (int kb = 0; kb < K / 32; kb++) {
    bf16x8 a = *(const bf16x8*)(xrow + kb * 32);
    #pragma unroll
    for (int st = 0; st < 4; st++) {
      bf16x8 bfr = *(const bf16x8*)(wrow + (size_t)(st * 16 + l15) * K + kb * 32);
      acc[st] = __builtin_amdgcn_mfma_f32_16x16x32_bf16(a, bfr, acc[st], 0, 0, 0);
    }
  }
  // epilogue values: row t = t0 + l4*4 + r, col j = wv*64 + st*16 + l15
  float val[4][4];
  #pragma unroll
  for (int st = 0; st < 4; st++) {
    int j = wv * 64 + st * 16 + l15;
    float bv_ = bias[j];
    #pragma unroll
    for (int r = 0; r < 4; r++) {
      float v = acc[st][r] + bv_;
      if (GELU_PRE) v = geluf(v);
      if (HAS_RES) v += res[(size_t)(t0 + l4 * 4 + r) * E_ + j];
      val[st][r] = v;
    }
  }
  // LN pass 1: row sums (cross-wave via LDS)
  #pragma unroll
  for (int r = 0; r < 4; r++) {
    float s = val[0][r] + val[1][r] + val[2][r] + val[3][r];
    s = l15_sum(s);
    if (l15 == 0) redA[wv][l4 * 4 + r] = s;
  }
  __syncthreads();
  float mean[4];
  #pragma unroll
  for (int r = 0; r < 4; r++) {
    int row = l4 * 4 + r;
    mean[r] = (redA[0][row] + redA[1][row] + redA[2][row] + redA[3][row]) * (1.f / E_);
  }
  // LN pass 2: row sumsq
  #pragma unroll
  for (int r = 0; r < 4; r++) {
    float s = 0.f;
    #pragma unroll
    for (int st = 0; st < 4; st++) {
      float d = val[st][r] - mean[r];
      s += d * d;
    }
    s = l15_sum(s);
    if (l15 == 0) redB[wv][l4 * 4 + r] = s;
  }
  __syncthreads();
  float rstd[4];
  #pragma unroll
  for (int r = 0; r < 4; r++) {
    int row = l4 * 4 + r;
    float var = (redB[0][row] + redB[1][row] + redB[2][row] + redB[3][row]) * (1.f / E_);
    rstd[r] = 1.f / sqrtf(var + 1e-5f);
  }
  #pragma unroll
  for (int st = 0; st < 4; st++) {
    int j = wv * 64 + st * 16 + l15;
    float gj = g[j], bj = bet[j];
    #pragma unroll
    for (int r = 0; r < 4; r++) {
      int t = t0 + l4 * 4 + r;
      float o = (val[st][r] - mean[r]) * rstd[r] * gj + bj;
      if (OUT_F32) y[(size_t)t * E_ + j] = o;
      yb[(size_t)t * E_ + j] = f2bf(o);
    }
  }
}

// ---------------- MFMA attention: one block per (n, h) ----------------
__global__ __launch_bounds__(256) void k_attn(
    const ushort_t* __restrict__ qkv, ushort_t* __restrict__ o) {
  __shared__ __align__(16) ushort_t vt_[32 * 72];  // V^T [d][t]
  __shared__ __align__(16) ushort_t ps[64 * 72];   // P [s][t]
  int n = blockIdx.x >> 3, h = blockIdx.x & 7;
  int tid = threadIdx.x, lane = tid & 63, wv = tid >> 6;
  int l15 = lane & 15, l4 = lane >> 4;
  const ushort_t* qbase = qkv + (size_t)n * S_ * 768 + h * DH_;
  for (int i = tid; i < S_ * DH_; i += 256) {
    int t = i >> 5, d = i & 31;
    vt_[d * 72 + t] = qbase[(size_t)t * 768 + 512 + d];
  }
  int srow = wv * 16 + l15;
  bf16x8 aq = *(const bf16x8*)&qbase[(size_t)srow * 768 + l4 * 8];
  f32x4 sc[4];
  #pragma unroll
  for (int st = 0; st < 4; st++) {
    bf16x8 bk_ = *(const bf16x8*)&qbase[(size_t)(st * 16 + l15) * 768 + 256 + l4 * 8];
    f32x4 z = {};
    sc[st] = __builtin_amdgcn_mfma_f32_16x16x32_bf16(aq, bk_, z, 0, 0, 0);
  }
  const float scale = 0.17677669529663687f;  // 1/sqrt(32)
  #pragma unroll
  for (int st = 0; st < 4; st++)
    #pragma unroll
    for (int r = 0; r < 4; r++) sc[st][r] *= scale;
  #pragma unroll
  for (int r = 0; r < 4; r++) {
    float m = fmaxf(fmaxf(sc[0][r], sc[1][r]), fmaxf(sc[2][r], sc[3][r]));
    m = fmaxf(m, __shfl_xor(m, 1, 64));
    m = fmaxf(m, __shfl_xor(m, 2, 64));
    m = fmaxf(m, __shfl_xor(m, 4, 64));
    m = fmaxf(m, __shfl_xor(m, 8, 64));
    float p0 = __expf(sc[0][r] - m), p1 = __expf(sc[1][r] - m);
    float p2 = __expf(sc[2][r] - m), p3 = __expf(sc[3][r] - m);
    float sum = p0 + p1 + p2 + p3;
    sum += __shfl_xor(sum, 1, 64);
    sum += __shfl_xor(sum, 2, 64);
    sum += __shfl_xor(sum, 4, 64);
    sum += __shfl_xor(sum, 8, 64);
    float inv = 1.f / sum;
    int prow = (wv * 16 + l4 * 4 + r) * 72;
    ps[prow + 0 * 16 + l15] = f2bf(p0 * inv);
    ps[prow + 1 * 16 + l15] = f2bf(p1 * inv);
    ps[prow + 2 * 16 + l15] = f2bf(p2 * inv);
    ps[prow + 3 * 16 + l15] = f2bf(p3 * inv);
  }
  __syncthreads();
  f32x4 oc[2] = {};
  #pragma unroll
  for (int kb = 0; kb < 2; kb++) {
    bf16x8 ap = *(const bf16x8*)&ps[srow * 72 + kb * 32 + l4 * 8];
    #pragma unroll
    for (int st2 = 0; st2 < 2; st2++) {
      bf16x8 bv_ = *(const bf16x8*)&vt_[(st2 * 16 + l15) * 72 + kb * 32 + l4 * 8];
      oc[st2] = __builtin_amdgcn_mfma_f32_16x16x32_bf16(ap, bv_, oc[st2], 0, 0, 0);
    }
  }
  ushort_t* ob = o + (size_t)n * S_ * E_ + h * DH_;
  #pragma unroll
  for (int st2 = 0; st2 < 2; st2++)
    #pragma unroll
    for (int r = 0; r < 4; r++)
      ob[(size_t)(wv * 16 + l4 * 4 + r) * E_ + st2 * 16 + l15] = f2bf(oc[st2][r]);
}

// ---------------- dW2 [E][V] f32 -> wt [VPAD][E] bf16 ----------------
__global__ __launch_bounds__(256) void k_w2t(const float* __restrict__ w,
                                             ushort_t* __restrict__ wt) {
  __shared__ float tile[32 * 33];
  int tx = threadIdx.x & 31, ty = threadIdx.x >> 5;
  int v0 = blockIdx.x * 32, k0 = blockIdx.y * 32;
  #pragma unroll
  for (int rr = 0; rr < 4; rr++) {
    int kk = ty * 4 + rr;
    int vv = v0 + tx;
    tile[kk * 33 + tx] = (vv < V_) ? w[(size_t)(k0 + kk) * V_ + vv] : 0.f;
  }
  __syncthreads();
  #pragma unroll
  for (int rr = 0; rr < 4; rr++) {
    int vv = ty * 4 + rr;
    wt[(size_t)(v0 + vv) * E_ + k0 + tx] = f2bf(tile[tx * 33 + vv]);
  }
}

// ---------------- vocab GEMM: 256v x 64s per block, two 128-v halves -------------
__global__ __launch_bounds__(256) void k_vocab(
    const ushort_t* __restrict__ hbf, const ushort_t* __restrict__ wt,
    const float* __restrict__ db2, float* __restrict__ out,
    float* __restrict__ pmax, float* __restrict__ psum) {
  __shared__ ushort_t hs[64 * 264];
  __shared__ float redm[4][64];
  __shared__ float reds[4][64];
  int n = blockIdx.x, vt = blockIdx.y;
  int tid = threadIdx.x, lane = tid & 63, wv = tid >> 6;
  const ushort_t* hsrc = hbf + (size_t)n * S_ * E_;
  for (int i = tid; i < (S_ * E_) / 8; i += 256) {
    int s = i >> 5, kc = (i & 31) * 8;
    *(uint4*)&hs[s * 264 + kc] = *(const uint4*)&hsrc[s * E_ + kc];
  }
  __syncthreads();
  int l15 = lane & 15, l4 = lane >> 4;
  float rm[4], rs[4];
  #pragma unroll
  for (int st = 0; st < 4; st++) { rm[st] = -INFINITY; rs[st] = 0.f; }
  #pragma unroll
  for (int h2 = 0; h2 < 2; h2++) {
    const ushort_t* Ap0 =
        wt + (size_t)(vt * 256 + h2 * 128 + wv * 16 + l15) * E_ + l4 * 8;
    const ushort_t* Ap1 = Ap0 + (size_t)64 * E_;
    f32x4 acc[2][4] = {};
    #pragma unroll
    for (int kb = 0; kb < 8; kb++) {
      bf16x8 a0 = *(const bf16x8*)(Ap0 + kb * 32);
      bf16x8 a1 = *(const bf16x8*)(Ap1 + kb * 32);
      #pragma unroll
      for (int st = 0; st < 4; st++) {
        bf16x8 bfr = *(const bf16x8*)&hs[(st * 16 + l15) * 264 + kb * 32 + l4 * 8];
        acc[0][st] = __builtin_amdgcn_mfma_f32_16x16x32_bf16(a0, bfr, acc[0][st], 0, 0, 0);
        acc[1][st] = __builtin_amdgcn_mfma_f32_16x16x32_bf16(a1, bfr, acc[1][st], 0, 0, 0);
      }
    }
    float vals[2][4][4];
    #pragma unroll
    for (int mt = 0; mt < 2; mt++) {
      #pragma unroll
      for (int j = 0; j < 4; j++) {
        int v = vt * 256 + h2 * 128 + wv * 16 + mt * 64 + l4 * 4 + j;
        bool valid = v < V_;
        float bias = valid ? db2[v] : 0.f;
        size_t ob = ((size_t)n * V_ + v) * S_;
        #pragma unroll
        for (int st = 0; st < 4; st++) {
          float val = valid ? (acc[mt][st][j] + bias) : -INFINITY;
          vals[mt][st][j] = val;
          if (valid) __builtin_nontemporal_store(val, &out[ob + st * 16 + l15]);
        }
      }
    }
    #pragma unroll
    for (int st = 0; st < 4; st++) {
      float m = -INFINITY;
      #pragma unroll
      for (int mt = 0; mt < 2; mt++)
        #pragma unroll
        for (int j = 0; j < 4; j++) m = fmaxf(m, vals[mt][st][j]);
      m = fmaxf(m, __shfl_xor(m, 16, 64));
      m = fmaxf(m, __shfl_xor(m, 32, 64));
      float sum = 0.f;
      #pragma unroll
      for (int mt = 0; mt < 2; mt++)
        #pragma unroll
        for (int j = 0; j < 4; j++) sum += __expf(vals[mt][st][j] - m);
      sum += __shfl_xor(sum, 16, 64);
      sum += __shfl_xor(sum, 32, 64);
      float nm = fmaxf(rm[st], m);
      rs[st] = rs[st] * __expf(rm[st] - nm) + sum * __expf(m - nm);
      rm[st] = nm;
    }
  }
  if (l4 == 0) {
    #pragma unroll
    for (int st = 0; st < 4; st++) {
      redm[wv][st * 16 + l15] = rm[st];
      reds[wv][st * 16 + l15] = rs[st];
    }
  }
  __syncthreads();
  if (wv == 0 && l4 == 0) {
    #pragma unroll
    for (int st = 0; st < 4; st++) {
      int s = st * 16 + l15;
      float M = fmaxf(fmaxf(redm[0][s], redm[1][s]), fmaxf(redm[2][s], redm[3][s]));
      float Sa = reds[0][s] * __expf(redm[0][s] - M) +
                 reds[1][s] * __expf(redm[1][s] - M) +
                 reds[2][s] * __expf(redm[2][s] - M) +
                 reds[3][s] * __expf(redm[3][s] - M);
      size_t pi = ((size_t)n * NVT_ + vt) * S_ + s;
      pmax[pi] = M;
      psum[pi] = Sa;
    }
  }
}

// ---------------- loss finalize (512 threads) ----------------
__global__ __launch_bounds__(512) void k_lossf(
    const float* __restrict__ pmax, const float* __restrict__ psum,
    const float* __restrict__ out, const int* __restrict__ label,
    float* __restrict__ partial) {
  __shared__ float sm[512], ssum[512];
  int n = blockIdx.x, tid = threadIdx.x;
  int s = tid & 63, qq = tid >> 6;  // qq in [0,8)
  float m = -INFINITY, sum = 0.f;
  for (int vt = qq; vt < NVT_; vt += 8) {
    size_t pi = ((size_t)n * NVT_ + vt) * S_ + s;
    float m2 = pmax[pi], s2 = psum[pi];
    float nm = fmaxf(m, m2);
    sum = sum * __expf(m - nm) + s2 * __expf(m2 - nm);
    m = nm;
  }
  sm[tid] = m; ssum[tid] = sum;
  __syncthreads();
  if (qq == 0) {
    float M = sm[s], Sa = ssum[s];
    #pragma unroll
    for (int p = 1; p < 8; p++) {
      float m2 = sm[p * 64 + s], s2 = ssum[p * 64 + s];
      float nm = fmaxf(M, m2);
      Sa = Sa * __expf(M - nm) + s2 * __expf(m2 - nm);
      M = nm;
    }
    float lse = M + logf(Sa);
    int lab = label[n * S_ + s];
    float lx = out[((size_t)n * V_ + lab) * S_ + s];
    partial[n * S_ + s] = lse - lx;
  }
}

__global__ __launch_bounds__(256) void k_loss2(const float* __restrict__ partial,
                                               float* __restrict__ dst) {
  __shared__ float sbuf[4];
  int tid = threadIdx.x;
  float acc = 0.f;
  for (int i = tid; i < T_; i += 256) acc += partial[i];
  #pragma unroll
  for (int off = 32; off >= 1; off >>= 1) acc += __shfl_xor(acc, off, 64);
  int lane = tid & 63, wid = tid >> 6;
  if (lane == 0) sbuf[wid] = acc;
  __syncthreads();
  if (tid == 0) dst[0] = (sbuf[0] + sbuf[1] + sbuf[2] + sbuf[3]) / (float)T_;
}

extern "C" void kernel_launch(void* const* d_in, const int* in_sizes, int n_in,
                              void* d_out, int out_size, void* d_ws, size_t ws_size,
                              hipStream_t stream) {
  const int*   label = (const int*)d_in[0];
  const int*   mask  = (const int*)d_in[1];
  const float* emb   = (const float*)d_in[2];
  const float* pos   = (const float*)d_in[3];
  const float* emb_g = (const float*)d_in[4];
  const float* emb_b = (const float*)d_in[5];
  const float* Wq  = (const float*)d_in[6];
  const float* bq  = (const float*)d_in[7];
  const float* Wk  = (const float*)d_in[8];
  const float* bk  = (const float*)d_in[9];
  const float* Wv  = (const float*)d_in[10];
  const float* bv  = (const float*)d_in[11];
  const float* Wo  = (const float*)d_in[12];
  const float* bo  = (const float*)d_in[13];
  const float* n1g = (const float*)d_in[14];
  const float* n1b = (const float*)d_in[15];
  const float* W1  = (const float*)d_in[16];
  const float* b1  = (const float*)d_in[17];
  const float* W2  = (const float*)d_in[18];
  const float* b2  = (const float*)d_in[19];
  const float* n2g = (const float*)d_in[20];
  const float* n2b = (const float*)d_in[21];
  const float* dW1 = (const float*)d_in[22];
  const float* db1 = (const float*)d_in[23];
  const float* dng = (const float*)d_in[24];
  const float* dnb = (const float*)d_in[25];
  const float* dW2 = (const float*)d_in[26];
  const float* db2 = (const float*)d_in[27];
  float* out = (float*)d_out;
  (void)in_sizes; (void)n_in; (void)out_size; (void)ws_size;

  char* base = (char*)d_ws;
  size_t off = 0;
  auto alloc = [&](size_t bytes) {
    char* p = base + off;
    off += (bytes + 255) & ~(size_t)255;
    return p;
  };
  float*    x    = (float*)alloc((size_t)T_ * E_ * 4);
  ushort_t* xb   = (ushort_t*)alloc((size_t)T_ * E_ * 2);
  float*    x1   = (float*)alloc((size_t)T_ * E_ * 4);
  ushort_t* x1b  = (ushort_t*)alloc((size_t)T_ * E_ * 2);
  ushort_t* qkv  = (ushort_t*)alloc((size_t)T_ * 768 * 2);
  ushort_t* obuf = (ushort_t*)alloc((size_t)T_ * E_ * 2);
  ushort_t* wqkvT = (ushort_t*)alloc((size_t)L_ * 768 * E_ * 2);
  ushort_t* woT   = (ushort_t*)alloc((size_t)L_ * E_ * E_ * 2);
  ushort_t* w1T   = (ushort_t*)alloc((size_t)L_ * H_ * E_ * 2);
  ushort_t* w2T   = (ushort_t*)alloc((size_t)L_ * E_ * H_ * 2);
  ushort_t* dw1T  = (ushort_t*)alloc((size_t)E_ * E_ * 2);
  ushort_t* wt    = (ushort_t*)alloc((size_t)VPAD_ * E_ * 2);
  float*    bqkv  = (float*)alloc((size_t)L_ * 768 * 4);
  float*    partial = (float*)alloc((size_t)T_ * 4);
  ushort_t* ffh = qkv;        // alias: qkv dead after attn
  ushort_t* hbf = obuf;       // alias: obuf dead after the loop
  float* pmax = x;            // alias: x/x1 span dead by k_vocab (~8.6 MB needed)
  float* psum = pmax + (size_t)N_ * NVT_ * S_;

  // ---- one-time weight prep (5 launches) ----
  k_bcat<<<L_, 256, 0, stream>>>(bq, bk, bv, bqkv);
  k_wtE<<<dim3(8, 8, 4 * L_ + 1), 256, 0, stream>>>(Wq, Wk, Wv, Wo, dW1, wqkvT, woT, dw1T);
  k_wt<<<dim3(16, 8, L_), 256, 0, stream>>>(W1, w1T, E_, H_, H_ * E_);
  k_wt<<<dim3(8, 16, L_), 256, 0, stream>>>(W2, w2T, H_, E_, E_ * H_);
  k_w2t<<<dim3(VPAD_ / 32, E_ / 32), 256, 0, stream>>>(dW2, wt);

  k_embed_ln<<<T_ / 4, 256, 0, stream>>>(label, mask, emb, pos, emb_g, emb_b, x, xb);

  for (int l = 0; l < L_; l++) {
    k_mm<E_, 1, 0><<<dim3(T_ / 64, 12), 256, 0, stream>>>(
        xb, wqkvT + (size_t)l * 768 * E_, bqkv + l * 768, qkv, 768);
    k_attn<<<N_ * NH_, 256, 0, stream>>>(qkv, obuf);
    // Wo + residual(x) + LN1 -> x1 (f32) + x1b (bf16)
    k_mm_ln2<E_, 0, 1, 1><<<T_ / 16, 256, 0, stream>>>(
        obuf, woT + (size_t)l * E_ * E_, bo + l * E_, x,
        n1g + l * E_, n1b + l * E_, x1, x1b);
    k_mm<E_, 1, 1><<<dim3(T_ / 64, 8), 256, 0, stream>>>(
        x1b, w1T + (size_t)l * H_ * E_, b1 + l * H_, ffh, H_);
    // FF2 + residual(x1) + LN2 -> x (f32) + xb (bf16)
    k_mm_ln2<H_, 0, 1, 1><<<T_ / 16, 256, 0, stream>>>(
        ffh, w2T + (size_t)l * E_ * H_, b2 + l * E_, x1,
        n2g + l * E_, n2b + l * E_, x, xb);
  }

  // decoder head: LN(gelu(x @ dW1 + db1)) -> hbf (bf16)
  k_mm_ln2<E_, 1, 0, 0><<<T_ / 16, 256, 0, stream>>>(
      xb, dw1T, db1, nullptr, dng, dnb, nullptr, hbf);

  // vocab projection + transposed store + fused softmax partials
  k_vocab<<<dim3(N_, NVT_), 256, 0, stream>>>(hbf, wt, db2, out, pmax, psum);

  // loss
  k_lossf<<<N_, 512, 0, stream>>>(pmax, psum, out, label, partial);
  k_loss2<<<1, 256, 0, stream>>>(partial, out + (size_t)N_ * V_ * S_);
}

// Round 8
// 850.134 us; speedup vs baseline: 1.4052x; 1.0300x over previous
//
#include <hip/hip_runtime.h>
#include <hip/hip_bf16.h>

#define DEVFN static __device__ __forceinline__

constexpr int N_ = 128, S_ = 64, T_ = N_ * S_;
constexpr int E_ = 256, H_ = 512, NH_ = 8, DH_ = 32, L_ = 4;
constexpr int V_ = 33279, VPAD_ = 33280, NVT_ = VPAD_ / 256;  // 130 v-tiles of 256

typedef __attribute__((ext_vector_type(8))) short bf16x8;
typedef __attribute__((ext_vector_type(4))) float f32x4;
typedef unsigned short ushort_t;

DEVFN ushort_t f2bf(float f) {
  unsigned int u = __float_as_uint(f);
  unsigned int r = (u + 0x7fffu + ((u >> 16) & 1u)) >> 16;
  return (ushort_t)r;
}
DEVFN float bf2f(ushort_t u) { return __uint_as_float(((unsigned)u) << 16); }

DEVFN float geluf(float x) {
  return 0.5f * x * (1.f + erff(x * 0.70710678118654752440f));
}

DEVFN float wave_sum(float v) {
  #pragma unroll
  for (int off = 32; off >= 1; off >>= 1) v += __shfl_xor(v, off, 64);
  return v;
}

DEVFN float l15_sum(float v) {
  v += __shfl_xor(v, 1, 64);
  v += __shfl_xor(v, 2, 64);
  v += __shfl_xor(v, 4, 64);
  v += __shfl_xor(v, 8, 64);
  return v;
}

// ---------------- embedding + LN: one wave per token row ----------------
__global__ __launch_bounds__(256) void k_embed_ln(
    const int* __restrict__ label, const int* __restrict__ mask,
    const float* __restrict__ emb, const float* __restrict__ pos,
    const float* __restrict__ g, const float* __restrict__ b,
    float* __restrict__ x, ushort_t* __restrict__ xb) {
  int wv = threadIdx.x >> 6, lane = threadIdx.x & 63;
  int t = blockIdx.x * 4 + wv;
  int s = t & (S_ - 1);
  int id = (mask[t] == 1) ? V_ : label[t];
  int c = lane * 4;
  float4 v = *(const float4*)&emb[(size_t)id * E_ + c];
  float4 p = *(const float4*)&pos[s * E_ + c];
  v.x += p.x; v.y += p.y; v.z += p.z; v.w += p.w;
  float mean = wave_sum(v.x + v.y + v.z + v.w) * (1.f / E_);
  float4 d = {v.x - mean, v.y - mean, v.z - mean, v.w - mean};
  float var = wave_sum(d.x * d.x + d.y * d.y + d.z * d.z + d.w * d.w) * (1.f / E_);
  float rstd = 1.f / sqrtf(var + 1e-5f);
  float4 g4 = *(const float4*)&g[c];
  float4 b4 = *(const float4*)&b[c];
  float4 y = {d.x * rstd * g4.x + b4.x, d.y * rstd * g4.y + b4.y,
              d.z * rstd * g4.z + b4.z, d.w * rstd * g4.w + b4.w};
  *(float4*)&x[(size_t)t * E_ + c] = y;
  ushort4 yb = {f2bf(y.x), f2bf(y.y), f2bf(y.z), f2bf(y.w)};
  *(ushort4*)&xb[(size_t)t * E_ + c] = yb;
}

// ---------------- unified weight prep: all transposes + bias concat --------------
// grid (16,16,26): z<17 -> ExE (8x8 tiles); z in [17,21) -> W1 layer; [21,25) -> W2;
// z==25 -> bias concat. Idle blocks exit.
__global__ __launch_bounds__(256) void k_prep(
    const float* __restrict__ Wq, const float* __restrict__ Wk,
    const float* __restrict__ Wv, const float* __restrict__ Wo,
    const float* __restrict__ dW1, const float* __restrict__ W1,
    const float* __restrict__ W2, const float* __restrict__ bq,
    const float* __restrict__ bk, const float* __restrict__ bv,
    ushort_t* __restrict__ wqkvT, ushort_t* __restrict__ woT,
    ushort_t* __restrict__ dw1T, ushort_t* __restrict__ w1T,
    ushort_t* __restrict__ w2T, float* __restrict__ bqkv) {
  int z = blockIdx.z;
  if (z == 25) {
    if (blockIdx.x == 0 && blockIdx.y == 0) {
      for (int i = threadIdx.x; i < L_ * 768; i += 256) {
        int l = i / 768, c = i - l * 768;
        float v = (c < 256) ? bq[l * 256 + c]
                : (c < 512) ? bk[l * 256 + c - 256]
                            : bv[l * 256 + c - 512];
        bqkv[i] = v;
      }
    }
    return;
  }
  const float* src;
  ushort_t* dst;
  int K, J;
  if (z < 17) {
    if (blockIdx.x >= 8 || blockIdx.y >= 8) return;
    K = 256; J = 256;
    if (z == 16) { src = dW1; dst = dw1T; }
    else {
      int w = z >> 2, l = z & 3;
      const float* ws = (w == 0) ? Wq : (w == 1) ? Wk : (w == 2) ? Wv : Wo;
      src = ws + (size_t)l * 65536;
      dst = (w < 3) ? (wqkvT + (size_t)l * 768 * 256 + (size_t)w * 256 * 256)
                    : (woT + (size_t)l * 65536);
    }
  } else if (z < 21) {
    int l = z - 17; K = 256; J = 512;
    if (blockIdx.y >= 8) return;
    src = W1 + (size_t)l * K * J; dst = w1T + (size_t)l * J * K;
  } else {
    int l = z - 21; K = 512; J = 256;
    if (blockIdx.x >= 8) return;
    src = W2 + (size_t)l * K * J; dst = w2T + (size_t)l * J * K;
  }
  __shared__ float tile[32][33];
  int j0 = blockIdx.x * 32, k0 = blockIdx.y * 32;
  int tx = threadIdx.x & 31, ty = threadIdx.x >> 5;
  #pragma unroll
  for (int rr = 0; rr < 4; rr++) {
    int kk = ty * 4 + rr;
    tile[kk][tx] = src[(size_t)(k0 + kk) * J + j0 + tx];
  }
  __syncthreads();
  #pragma unroll
  for (int rr = 0; rr < 4; rr++) {
    int jj = ty * 4 + rr;
    dst[(size_t)(j0 + jj) * K + k0 + tx] = f2bf(tile[tx][jj]);
  }
}

// ---------------- MFMA GEMM: C[T][Nout] = Xb[T][K] @ WT[Nout][K]^T + bias --------
template <int K, int OUT_BF16, int GELU_>
__global__ __launch_bounds__(256) void k_mm(
    const ushort_t* __restrict__ Xb, const ushort_t* __restrict__ WT,
    const float* __restrict__ bias, void* __restrict__ C, int Nout) {
  constexpr int STR = K + 8;
  __shared__ ushort_t xs[64 * STR];
  int tid = threadIdx.x, lane = tid & 63, wv = tid >> 6;
  int t0 = blockIdx.x * 64, j0 = blockIdx.y * 64;
  const ushort_t* xsrc = Xb + (size_t)t0 * K;
  for (int i = tid; i < 64 * (K / 8); i += 256) {
    int r = i / (K / 8), c = (i % (K / 8)) * 8;
    *(uint4*)&xs[r * STR + c] = *(const uint4*)&xsrc[(size_t)r * K + c];
  }
  __syncthreads();
  int l15 = lane & 15, l4 = lane >> 4;
  f32x4 acc[4] = {};
  const ushort_t* xrow = &xs[(wv * 16 + l15) * STR + l4 * 8];
  const ushort_t* wrow = WT + (size_t)j0 * K + l4 * 8;
  #pragma unroll
  for (int kb = 0; kb < K / 32; kb++) {
    bf16x8 a = *(const bf16x8*)(xrow + kb * 32);
    #pragma unroll
    for (int st = 0; st < 4; st++) {
      bf16x8 bfr = *(const bf16x8*)(wrow + (size_t)(st * 16 + l15) * K + kb * 32);
      acc[st] = __builtin_amdgcn_mfma_f32_16x16x32_bf16(a, bfr, acc[st], 0, 0, 0);
    }
  }
  #pragma unroll
  for (int st = 0; st < 4; st++) {
    int j = j0 + st * 16 + l15;
    float bv_ = bias[j];
    #pragma unroll
    for (int r = 0; r < 4; r++) {
      float val = acc[st][r] + bv_;
      if (GELU_) val = geluf(val);
      int t = t0 + wv * 16 + l4 * 4 + r;
      if (OUT_BF16)
        ((ushort_t*)C)[(size_t)t * Nout + j] = f2bf(val);
      else
        ((float*)C)[(size_t)t * Nout + j] = val;
    }
  }
}

// ------- fused GEMM (Nout=256) + [gelu] + [residual] + LN, 16 rows/block --------
template <int K, int GELU_PRE, int HAS_RES, int OUT_F32>
__global__ __launch_bounds__(256) void k_mm_ln2(
    const ushort_t* __restrict__ Xb, const ushort_t* __restrict__ WT,
    const float* __restrict__ bias, const float* __restrict__ res,
    const float* __restrict__ g, const float* __restrict__ bet,
    float* __restrict__ y, ushort_t* __restrict__ yb) {
  constexpr int STR = K + 8;
  __shared__ ushort_t xs[16 * STR];
  __shared__ float redA[4][16], redB[4][16];
  int tid = threadIdx.x, lane = tid & 63, wv = tid >> 6;
  int t0 = blockIdx.x * 16;
  const ushort_t* xsrc = Xb + (size_t)t0 * K;
  for (int i = tid; i < 16 * (K / 8); i += 256) {
    int r = i / (K / 8), c = (i % (K / 8)) * 8;
    *(uint4*)&xs[r * STR + c] = *(const uint4*)&xsrc[(size_t)r * K + c];
  }
  __syncthreads();
  int l15 = lane & 15, l4 = lane >> 4;
  f32x4 acc[4] = {};
  const ushort_t* xrow = &xs[l15 * STR + l4 * 8];
  const ushort_t* wrow = WT + (size_t)(wv * 64) * K + l4 * 8;
  #pragma unroll
  for (int kb = 0; kb < K / 32; kb++) {
    bf16x8 a = *(const bf16x8*)(xrow + kb * 32);
    #pragma unroll
    for (int st = 0; st < 4; st++) {
      bf16x8 bfr = *(const bf16x8*)(wrow + (size_t)(st * 16 + l15) * K + kb * 32);
      acc[st] = __builtin_amdgcn_mfma_f32_16x16x32_bf16(a, bfr, acc[st], 0, 0, 0);
    }
  }
  float val[4][4];
  #pragma unroll
  for (int st = 0; st < 4; st++) {
    int j = wv * 64 + st * 16 + l15;
    float bv_ = bias[j];
    #pragma unroll
    for (int r = 0; r < 4; r++) {
      float v = acc[st][r] + bv_;
      if (GELU_PRE) v = geluf(v);
      if (HAS_RES) v += res[(size_t)(t0 + l4 * 4 + r) * E_ + j];
      val[st][r] = v;
    }
  }
  #pragma unroll
  for (int r = 0; r < 4; r++) {
    float s = val[0][r] + val[1][r] + val[2][r] + val[3][r];
    s = l15_sum(s);
    if (l15 == 0) redA[wv][l4 * 4 + r] = s;
  }
  __syncthreads();
  float mean[4];
  #pragma unroll
  for (int r = 0; r < 4; r++) {
    int row = l4 * 4 + r;
    mean[r] = (redA[0][row] + redA[1][row] + redA[2][row] + redA[3][row]) * (1.f / E_);
  }
  #pragma unroll
  for (int r = 0; r < 4; r++) {
    float s = 0.f;
    #pragma unroll
    for (int st = 0; st < 4; st++) {
      float d = val[st][r] - mean[r];
      s += d * d;
    }
    s = l15_sum(s);
    if (l15 == 0) redB[wv][l4 * 4 + r] = s;
  }
  __syncthreads();
  float rstd[4];
  #pragma unroll
  for (int r = 0; r < 4; r++) {
    int row = l4 * 4 + r;
    float var = (redB[0][row] + redB[1][row] + redB[2][row] + redB[3][row]) * (1.f / E_);
    rstd[r] = 1.f / sqrtf(var + 1e-5f);
  }
  #pragma unroll
  for (int st = 0; st < 4; st++) {
    int j = wv * 64 + st * 16 + l15;
    float gj = g[j], bj = bet[j];
    #pragma unroll
    for (int r = 0; r < 4; r++) {
      int t = t0 + l4 * 4 + r;
      float o = (val[st][r] - mean[r]) * rstd[r] * gj + bj;
      if (OUT_F32) y[(size_t)t * E_ + j] = o;
      yb[(size_t)t * E_ + j] = f2bf(o);
    }
  }
}

// -------- fused FFN: gelu(X@W1+b1)@W2 + b2 + residual + LN, 16 rows/block -------
// 4 waves. FF1: wave owns 128 hidden cols; hidden tile in LDS; FF2: wave owns 64
// out cols; then cross-wave LN (same pattern as k_mm_ln2).
__global__ __launch_bounds__(256) void k_ff(
    const ushort_t* __restrict__ Xb, const ushort_t* __restrict__ W1T,
    const float* __restrict__ b1v, const ushort_t* __restrict__ W2T,
    const float* __restrict__ b2v, const float* __restrict__ res,
    const float* __restrict__ g, const float* __restrict__ bet,
    float* __restrict__ y, ushort_t* __restrict__ yb) {
  __shared__ ushort_t xs[16 * 264];
  __shared__ ushort_t hsd[16 * 520];
  __shared__ float redA[4][16], redB[4][16];
  int tid = threadIdx.x, lane = tid & 63, wv = tid >> 6;
  int t0 = blockIdx.x * 16;
  const ushort_t* xsrc = Xb + (size_t)t0 * E_;
  for (int i = tid; i < 16 * 32; i += 256) {
    int r = i >> 5, c = (i & 31) * 8;
    *(uint4*)&xs[r * 264 + c] = *(const uint4*)&xsrc[(size_t)r * E_ + c];
  }
  __syncthreads();
  int l15 = lane & 15, l4 = lane >> 4;
  // FF1: hidden col = wv*128 + ht*16 + l15; row t = t0 + l4*4 + r
  f32x4 acc1[8] = {};
  const ushort_t* xrow = &xs[l15 * 264 + l4 * 8];
  const ushort_t* w1r = W1T + (size_t)(wv * 128) * E_ + l4 * 8;
  #pragma unroll
  for (int kb = 0; kb < 8; kb++) {
    bf16x8 a = *(const bf16x8*)(xrow + kb * 32);
    #pragma unroll
    for (int ht = 0; ht < 8; ht++) {
      bf16x8 b = *(const bf16x8*)(w1r + (size_t)(ht * 16 + l15) * E_ + kb * 32);
      acc1[ht] = __builtin_amdgcn_mfma_f32_16x16x32_bf16(a, b, acc1[ht], 0, 0, 0);
    }
  }
  #pragma unroll
  for (int ht = 0; ht < 8; ht++) {
    int hc = wv * 128 + ht * 16 + l15;
    float bv_ = b1v[hc];
    #pragma unroll
    for (int r = 0; r < 4; r++) {
      float v = geluf(acc1[ht][r] + bv_);
      hsd[(l4 * 4 + r) * 520 + hc] = f2bf(v);
    }
  }
  __syncthreads();
  // FF2: out col j = wv*64 + st*16 + l15, K = 512
  f32x4 acc2[4] = {};
  const ushort_t* hrow = &hsd[l15 * 520 + l4 * 8];
  const ushort_t* w2r = W2T + (size_t)(wv * 64) * H_ + l4 * 8;
  #pragma unroll
  for (int kb = 0; kb < 16; kb++) {
    bf16x8 a = *(const bf16x8*)(hrow + kb * 32);
    #pragma unroll
    for (int st = 0; st < 4; st++) {
      bf16x8 b = *(const bf16x8*)(w2r + (size_t)(st * 16 + l15) * H_ + kb * 32);
      acc2[st] = __builtin_amdgcn_mfma_f32_16x16x32_bf16(a, b, acc2[st], 0, 0, 0);
    }
  }
  float val[4][4];
  #pragma unroll
  for (int st = 0; st < 4; st++) {
    int j = wv * 64 + st * 16 + l15;
    float bv_ = b2v[j];
    #pragma unroll
    for (int r = 0; r < 4; r++)
      val[st][r] = acc2[st][r] + bv_ + res[(size_t)(t0 + l4 * 4 + r) * E_ + j];
  }
  #pragma unroll
  for (int r = 0; r < 4; r++) {
    float s = val[0][r] + val[1][r] + val[2][r] + val[3][r];
    s = l15_sum(s);
    if (l15 == 0) redA[wv][l4 * 4 + r] = s;
  }
  __syncthreads();
  float mean[4];
  #pragma unroll
  for (int r = 0; r < 4; r++) {
    int row = l4 * 4 + r;
    mean[r] = (redA[0][row] + redA[1][row] + redA[2][row] + redA[3][row]) * (1.f / E_);
  }
  #pragma unroll
  for (int r = 0; r < 4; r++) {
    float s = 0.f;
    #pragma unroll
    for (int st = 0; st < 4; st++) {
      float d = val[st][r] - mean[r];
      s += d * d;
    }
    s = l15_sum(s);
    if (l15 == 0) redB[wv][l4 * 4 + r] = s;
  }
  __syncthreads();
  float rstd[4];
  #pragma unroll
  for (int r = 0; r < 4; r++) {
    int row = l4 * 4 + r;
    float var = (redB[0][row] + redB[1][row] + redB[2][row] + redB[3][row]) * (1.f / E_);
    rstd[r] = 1.f / sqrtf(var + 1e-5f);
  }
  #pragma unroll
  for (int st = 0; st < 4; st++) {
    int j = wv * 64 + st * 16 + l15;
    float gj = g[j], bj = bet[j];
    #pragma unroll
    for (int r = 0; r < 4; r++) {
      int t = t0 + l4 * 4 + r;
      float o = (val[st][r] - mean[r]) * rstd[r] * gj + bj;
      y[(size_t)t * E_ + j] = o;
      yb[(size_t)t * E_ + j] = f2bf(o);
    }
  }
}

// ---------------- MFMA attention: one block per (n, h) ----------------
__global__ __launch_bounds__(256) void k_attn(
    const ushort_t* __restrict__ qkv, ushort_t* __restrict__ o) {
  __shared__ __align__(16) ushort_t vt_[32 * 72];  // V^T [d][t]
  __shared__ __align__(16) ushort_t ps[64 * 72];   // P [s][t]
  int n = blockIdx.x >> 3, h = blockIdx.x & 7;
  int tid = threadIdx.x, lane = tid & 63, wv = tid >> 6;
  int l15 = lane & 15, l4 = lane >> 4;
  const ushort_t* qbase = qkv + (size_t)n * S_ * 768 + h * DH_;
  for (int i = tid; i < S_ * DH_; i += 256) {
    int t = i >> 5, d = i & 31;
    vt_[d * 72 + t] = qbase[(size_t)t * 768 + 512 + d];
  }
  int srow = wv * 16 + l15;
  bf16x8 aq = *(const bf16x8*)&qbase[(size_t)srow * 768 + l4 * 8];
  f32x4 sc[4];
  #pragma unroll
  for (int st = 0; st < 4; st++) {
    bf16x8 bk_ = *(const bf16x8*)&qbase[(size_t)(st * 16 + l15) * 768 + 256 + l4 * 8];
    f32x4 z = {};
    sc[st] = __builtin_amdgcn_mfma_f32_16x16x32_bf16(aq, bk_, z, 0, 0, 0);
  }
  const float scale = 0.17677669529663687f;  // 1/sqrt(32)
  #pragma unroll
  for (int st = 0; st < 4; st++)
    #pragma unroll
    for (int r = 0; r < 4; r++) sc[st][r] *= scale;
  #pragma unroll
  for (int r = 0; r < 4; r++) {
    float m = fmaxf(fmaxf(sc[0][r], sc[1][r]), fmaxf(sc[2][r], sc[3][r]));
    m = fmaxf(m, __shfl_xor(m, 1, 64));
    m = fmaxf(m, __shfl_xor(m, 2, 64));
    m = fmaxf(m, __shfl_xor(m, 4, 64));
    m = fmaxf(m, __shfl_xor(m, 8, 64));
    float p0 = __expf(sc[0][r] - m), p1 = __expf(sc[1][r] - m);
    float p2 = __expf(sc[2][r] - m), p3 = __expf(sc[3][r] - m);
    float sum = p0 + p1 + p2 + p3;
    sum += __shfl_xor(sum, 1, 64);
    sum += __shfl_xor(sum, 2, 64);
    sum += __shfl_xor(sum, 4, 64);
    sum += __shfl_xor(sum, 8, 64);
    float inv = 1.f / sum;
    int prow = (wv * 16 + l4 * 4 + r) * 72;
    ps[prow + 0 * 16 + l15] = f2bf(p0 * inv);
    ps[prow + 1 * 16 + l15] = f2bf(p1 * inv);
    ps[prow + 2 * 16 + l15] = f2bf(p2 * inv);
    ps[prow + 3 * 16 + l15] = f2bf(p3 * inv);
  }
  __syncthreads();
  f32x4 oc[2] = {};
  #pragma unroll
  for (int kb = 0; kb < 2; kb++) {
    bf16x8 ap = *(const bf16x8*)&ps[srow * 72 + kb * 32 + l4 * 8];
    #pragma unroll
    for (int st2 = 0; st2 < 2; st2++) {
      bf16x8 bv_ = *(const bf16x8*)&vt_[(st2 * 16 + l15) * 72 + kb * 32 + l4 * 8];
      oc[st2] = __builtin_amdgcn_mfma_f32_16x16x32_bf16(ap, bv_, oc[st2], 0, 0, 0);
    }
  }
  ushort_t* ob = o + (size_t)n * S_ * E_ + h * DH_;
  #pragma unroll
  for (int st2 = 0; st2 < 2; st2++)
    #pragma unroll
    for (int r = 0; r < 4; r++)
      ob[(size_t)(wv * 16 + l4 * 4 + r) * E_ + st2 * 16 + l15] = f2bf(oc[st2][r]);
}

// ---------------- dW2 [E][V] f32 -> wt [VPAD][E] bf16 ----------------
__global__ __launch_bounds__(256) void k_w2t(const float* __restrict__ w,
                                             ushort_t* __restrict__ wt) {
  __shared__ float tile[32 * 33];
  int tx = threadIdx.x & 31, ty = threadIdx.x >> 5;
  int v0 = blockIdx.x * 32, k0 = blockIdx.y * 32;
  #pragma unroll
  for (int rr = 0; rr < 4; rr++) {
    int kk = ty * 4 + rr;
    int vv = v0 + tx;
    tile[kk * 33 + tx] = (vv < V_) ? w[(size_t)(k0 + kk) * V_ + vv] : 0.f;
  }
  __syncthreads();
  #pragma unroll
  for (int rr = 0; rr < 4; rr++) {
    int vv = ty * 4 + rr;
    wt[(size_t)(v0 + vv) * E_ + k0 + tx] = f2bf(tile[tx * 33 + vv]);
  }
}

// ---------------- vocab GEMM: 256v x 64s per block, two 128-v halves -------------
__global__ __launch_bounds__(256) void k_vocab(
    const ushort_t* __restrict__ hbf, const ushort_t* __restrict__ wt,
    const float* __restrict__ db2, float* __restrict__ out,
    float* __restrict__ pmax, float* __restrict__ psum) {
  __shared__ ushort_t hs[64 * 264];
  __shared__ float redm[4][64];
  __shared__ float reds[4][64];
  int n = blockIdx.x, vt = blockIdx.y;
  int tid = threadIdx.x, lane = tid & 63, wv = tid >> 6;
  const ushort_t* hsrc = hbf + (size_t)n * S_ * E_;
  for (int i = tid; i < (S_ * E_) / 8; i += 256) {
    int s = i >> 5, kc = (i & 31) * 8;
    *(uint4*)&hs[s * 264 + kc] = *(const uint4*)&hsrc[s * E_ + kc];
  }
  __syncthreads();
  int l15 = lane & 15, l4 = lane >> 4;
  float rm[4], rs[4];
  #pragma unroll
  for (int st = 0; st < 4; st++) { rm[st] = -INFINITY; rs[st] = 0.f; }
  #pragma unroll
  for (int h2 = 0; h2 < 2; h2++) {
    const ushort_t* Ap0 =
        wt + (size_t)(vt * 256 + h2 * 128 + wv * 16 + l15) * E_ + l4 * 8;
    const ushort_t* Ap1 = Ap0 + (size_t)64 * E_;
    f32x4 acc[2][4] = {};
    #pragma unroll
    for (int kb = 0; kb < 8; kb++) {
      bf16x8 a0 = *(const bf16x8*)(Ap0 + kb * 32);
      bf16x8 a1 = *(const bf16x8*)(Ap1 + kb * 32);
      #pragma unroll
      for (int st = 0; st < 4; st++) {
        bf16x8 bfr = *(const bf16x8*)&hs[(st * 16 + l15) * 264 + kb * 32 + l4 * 8];
        acc[0][st] = __builtin_amdgcn_mfma_f32_16x16x32_bf16(a0, bfr, acc[0][st], 0, 0, 0);
        acc[1][st] = __builtin_amdgcn_mfma_f32_16x16x32_bf16(a1, bfr, acc[1][st], 0, 0, 0);
      }
    }
    float vals[2][4][4];
    #pragma unroll
    for (int mt = 0; mt < 2; mt++) {
      #pragma unroll
      for (int j = 0; j < 4; j++) {
        int v = vt * 256 + h2 * 128 + wv * 16 + mt * 64 + l4 * 4 + j;
        bool valid = v < V_;
        float bias = valid ? db2[v] : 0.f;
        size_t ob = ((size_t)n * V_ + v) * S_;
        #pragma unroll
        for (int st = 0; st < 4; st++) {
          float val = valid ? (acc[mt][st][j] + bias) : -INFINITY;
          vals[mt][st][j] = val;
          if (valid) __builtin_nontemporal_store(val, &out[ob + st * 16 + l15]);
        }
      }
    }
    #pragma unroll
    for (int st = 0; st < 4; st++) {
      float m = -INFINITY;
      #pragma unroll
      for (int mt = 0; mt < 2; mt++)
        #pragma unroll
        for (int j = 0; j < 4; j++) m = fmaxf(m, vals[mt][st][j]);
      m = fmaxf(m, __shfl_xor(m, 16, 64));
      m = fmaxf(m, __shfl_xor(m, 32, 64));
      float sum = 0.f;
      #pragma unroll
      for (int mt = 0; mt < 2; mt++)
        #pragma unroll
        for (int j = 0; j < 4; j++) sum += __expf(vals[mt][st][j] - m);
      sum += __shfl_xor(sum, 16, 64);
      sum += __shfl_xor(sum, 32, 64);
      float nm = fmaxf(rm[st], m);
      rs[st] = rs[st] * __expf(rm[st] - nm) + sum * __expf(m - nm);
      rm[st] = nm;
    }
  }
  if (l4 == 0) {
    #pragma unroll
    for (int st = 0; st < 4; st++) {
      redm[wv][st * 16 + l15] = rm[st];
      reds[wv][st * 16 + l15] = rs[st];
    }
  }
  __syncthreads();
  if (wv == 0 && l4 == 0) {
    #pragma unroll
    for (int st = 0; st < 4; st++) {
      int s = st * 16 + l15;
      float M = fmaxf(fmaxf(redm[0][s], redm[1][s]), fmaxf(redm[2][s], redm[3][s]));
      float Sa = reds[0][s] * __expf(redm[0][s] - M) +
                 reds[1][s] * __expf(redm[1][s] - M) +
                 reds[2][s] * __expf(redm[2][s] - M) +
                 reds[3][s] * __expf(redm[3][s] - M);
      size_t pi = ((size_t)n * NVT_ + vt) * S_ + s;
      pmax[pi] = M;
      psum[pi] = Sa;
    }
  }
}

// ---------------- loss finalize (512 threads) ----------------
__global__ __launch_bounds__(512) void k_lossf(
    const float* __restrict__ pmax, const float* __restrict__ psum,
    const float* __restrict__ out, const int* __restrict__ label,
    float* __restrict__ partial) {
  __shared__ float sm[512], ssum[512];
  int n = blockIdx.x, tid = threadIdx.x;
  int s = tid & 63, qq = tid >> 6;  // qq in [0,8)
  float m = -INFINITY, sum = 0.f;
  for (int vt = qq; vt < NVT_; vt += 8) {
    size_t pi = ((size_t)n * NVT_ + vt) * S_ + s;
    float m2 = pmax[pi], s2 = psum[pi];
    float nm = fmaxf(m, m2);
    sum = sum * __expf(m - nm) + s2 * __expf(m2 - nm);
    m = nm;
  }
  sm[tid] = m; ssum[tid] = sum;
  __syncthreads();
  if (qq == 0) {
    float M = sm[s], Sa = ssum[s];
    #pragma unroll
    for (int p = 1; p < 8; p++) {
      float m2 = sm[p * 64 + s], s2 = ssum[p * 64 + s];
      float nm = fmaxf(M, m2);
      Sa = Sa * __expf(M - nm) + s2 * __expf(m2 - nm);
      M = nm;
    }
    float lse = M + logf(Sa);
    int lab = label[n * S_ + s];
    float lx = out[((size_t)n * V_ + lab) * S_ + s];
    partial[n * S_ + s] = lse - lx;
  }
}

__global__ __launch_bounds__(256) void k_loss2(const float* __restrict__ partial,
                                               float* __restrict__ dst) {
  __shared__ float sbuf[4];
  int tid = threadIdx.x;
  float acc = 0.f;
  for (int i = tid; i < T_; i += 256) acc += partial[i];
  #pragma unroll
  for (int off = 32; off >= 1; off >>= 1) acc += __shfl_xor(acc, off, 64);
  int lane = tid & 63, wid = tid >> 6;
  if (lane == 0) sbuf[wid] = acc;
  __syncthreads();
  if (tid == 0) dst[0] = (sbuf[0] + sbuf[1] + sbuf[2] + sbuf[3]) / (float)T_;
}

extern "C" void kernel_launch(void* const* d_in, const int* in_sizes, int n_in,
                              void* d_out, int out_size, void* d_ws, size_t ws_size,
                              hipStream_t stream) {
  const int*   label = (const int*)d_in[0];
  const int*   mask  = (const int*)d_in[1];
  const float* emb   = (const float*)d_in[2];
  const float* pos   = (const float*)d_in[3];
  const float* emb_g = (const float*)d_in[4];
  const float* emb_b = (const float*)d_in[5];
  const float* Wq  = (const float*)d_in[6];
  const float* bq  = (const float*)d_in[7];
  const float* Wk  = (const float*)d_in[8];
  const float* bk  = (const float*)d_in[9];
  const float* Wv  = (const float*)d_in[10];
  const float* bv  = (const float*)d_in[11];
  const float* Wo  = (const float*)d_in[12];
  const float* bo  = (const float*)d_in[13];
  const float* n1g = (const float*)d_in[14];
  const float* n1b = (const float*)d_in[15];
  const float* W1  = (const float*)d_in[16];
  const float* b1  = (const float*)d_in[17];
  const float* W2  = (const float*)d_in[18];
  const float* b2  = (const float*)d_in[19];
  const float* n2g = (const float*)d_in[20];
  const float* n2b = (const float*)d_in[21];
  const float* dW1 = (const float*)d_in[22];
  const float* db1 = (const float*)d_in[23];
  const float* dng = (const float*)d_in[24];
  const float* dnb = (const float*)d_in[25];
  const float* dW2 = (const float*)d_in[26];
  const float* db2 = (const float*)d_in[27];
  float* out = (float*)d_out;
  (void)in_sizes; (void)n_in; (void)out_size; (void)ws_size;

  char* base = (char*)d_ws;
  size_t off = 0;
  auto alloc = [&](size_t bytes) {
    char* p = base + off;
    off += (bytes + 255) & ~(size_t)255;
    return p;
  };
  float*    x    = (float*)alloc((size_t)T_ * E_ * 4);
  ushort_t* xb   = (ushort_t*)alloc((size_t)T_ * E_ * 2);
  float*    x1   = (float*)alloc((size_t)T_ * E_ * 4);
  ushort_t* x1b  = (ushort_t*)alloc((size_t)T_ * E_ * 2);
  ushort_t* qkv  = (ushort_t*)alloc((size_t)T_ * 768 * 2);
  ushort_t* obuf = (ushort_t*)alloc((size_t)T_ * E_ * 2);
  ushort_t* wqkvT = (ushort_t*)alloc((size_t)L_ * 768 * E_ * 2);
  ushort_t* woT   = (ushort_t*)alloc((size_t)L_ * E_ * E_ * 2);
  ushort_t* w1T   = (ushort_t*)alloc((size_t)L_ * H_ * E_ * 2);
  ushort_t* w2T   = (ushort_t*)alloc((size_t)L_ * E_ * H_ * 2);
  ushort_t* dw1T  = (ushort_t*)alloc((size_t)E_ * E_ * 2);
  ushort_t* wt    = (ushort_t*)alloc((size_t)VPAD_ * E_ * 2);
  float*    bqkv  = (float*)alloc((size_t)L_ * 768 * 4);
  float*    partial = (float*)alloc((size_t)T_ * 4);
  ushort_t* hbf = obuf;       // alias: obuf dead after the loop
  float* pmax = x;            // alias: x/x1 span dead by k_vocab (~8.6 MB needed)
  float* psum = pmax + (size_t)N_ * NVT_ * S_;

  // ---- one-time weight prep (2 launches) ----
  k_prep<<<dim3(16, 16, 26), 256, 0, stream>>>(Wq, Wk, Wv, Wo, dW1, W1, W2,
                                               bq, bk, bv, wqkvT, woT, dw1T,
                                               w1T, w2T, bqkv);
  k_w2t<<<dim3(VPAD_ / 32, E_ / 32), 256, 0, stream>>>(dW2, wt);

  k_embed_ln<<<T_ / 4, 256, 0, stream>>>(label, mask, emb, pos, emb_g, emb_b, x, xb);

  for (int l = 0; l < L_; l++) {
    k_mm<E_, 1, 0><<<dim3(T_ / 64, 12), 256, 0, stream>>>(
        xb, wqkvT + (size_t)l * 768 * E_, bqkv + l * 768, qkv, 768);
    k_attn<<<N_ * NH_, 256, 0, stream>>>(qkv, obuf);
    // Wo + residual(x) + LN1 -> x1 (f32) + x1b (bf16)
    k_mm_ln2<E_, 0, 1, 1><<<T_ / 16, 256, 0, stream>>>(
        obuf, woT + (size_t)l * E_ * E_, bo + l * E_, x,
        n1g + l * E_, n1b + l * E_, x1, x1b);
    // fused FFN + residual(x1) + LN2 -> x (f32) + xb (bf16)
    k_ff<<<T_ / 16, 256, 0, stream>>>(
        x1b, w1T + (size_t)l * H_ * E_, b1 + l * H_,
        w2T + (size_t)l * E_ * H_, b2 + l * E_, x1,
        n2g + l * E_, n2b + l * E_, x, xb);
  }

  // decoder head: LN(gelu(x @ dW1 + db1)) -> hbf (bf16)
  k_mm_ln2<E_, 1, 0, 0><<<T_ / 16, 256, 0, stream>>>(
      xb, dw1T, db1, nullptr, dng, dnb, nullptr, hbf);

  // vocab projection + transposed store + fused softmax partials
  k_vocab<<<dim3(N_, NVT_), 256, 0, stream>>>(hbf, wt, db2, out, pmax, psum);

  // loss
  k_lossf<<<N_, 512, 0, stream>>>(pmax, psum, out, label, partial);
  k_loss2<<<1, 256, 0, stream>>>(partial, out + (size_t)N_ * V_ * S_);
}

// Round 9
// 827.401 us; speedup vs baseline: 1.4438x; 1.0275x over previous
//
#include <hip/hip_runtime.h>
#include <hip/hip_bf16.h>

#define DEVFN static __device__ __forceinline__
#define MFMA16(a, b, c) __builtin_amdgcn_mfma_f32_16x16x32_bf16((a), (b), (c), 0, 0, 0)

constexpr int N_ = 128, S_ = 64, T_ = N_ * S_;
constexpr int E_ = 256, H_ = 512, NH_ = 8, DH_ = 32, L_ = 4;
constexpr int V_ = 33279, VPAD_ = 33280, NVT_ = VPAD_ / 256;  // 130 v-tiles of 256

typedef __attribute__((ext_vector_type(8))) short bf16x8;
typedef __attribute__((ext_vector_type(4))) float f32x4;
typedef unsigned short ushort_t;

DEVFN ushort_t f2bf(float f) {
  unsigned int u = __float_as_uint(f);
  unsigned int r = (u + 0x7fffu + ((u >> 16) & 1u)) >> 16;
  return (ushort_t)r;
}
DEVFN float bf2f(ushort_t u) { return __uint_as_float(((unsigned)u) << 16); }

DEVFN float geluf(float x) {
  return 0.5f * x * (1.f + erff(x * 0.70710678118654752440f));
}

DEVFN float wave_sum(float v) {
  #pragma unroll
  for (int off = 32; off >= 1; off >>= 1) v += __shfl_xor(v, off, 64);
  return v;
}

DEVFN float l15_sum(float v) {
  v += __shfl_xor(v, 1, 64);
  v += __shfl_xor(v, 2, 64);
  v += __shfl_xor(v, 4, 64);
  v += __shfl_xor(v, 8, 64);
  return v;
}

// ---------------- embedding + LN: one wave per token row ----------------
__global__ __launch_bounds__(256) void k_embed_ln(
    const int* __restrict__ label, const int* __restrict__ mask,
    const float* __restrict__ emb, const float* __restrict__ pos,
    const float* __restrict__ g, const float* __restrict__ b,
    float* __restrict__ x, ushort_t* __restrict__ xb) {
  int wv = threadIdx.x >> 6, lane = threadIdx.x & 63;
  int t = blockIdx.x * 4 + wv;
  int s = t & (S_ - 1);
  int id = (mask[t] == 1) ? V_ : label[t];
  int c = lane * 4;
  float4 v = *(const float4*)&emb[(size_t)id * E_ + c];
  float4 p = *(const float4*)&pos[s * E_ + c];
  v.x += p.x; v.y += p.y; v.z += p.z; v.w += p.w;
  float mean = wave_sum(v.x + v.y + v.z + v.w) * (1.f / E_);
  float4 d = {v.x - mean, v.y - mean, v.z - mean, v.w - mean};
  float var = wave_sum(d.x * d.x + d.y * d.y + d.z * d.z + d.w * d.w) * (1.f / E_);
  float rstd = 1.f / sqrtf(var + 1e-5f);
  float4 g4 = *(const float4*)&g[c];
  float4 b4 = *(const float4*)&b[c];
  float4 y = {d.x * rstd * g4.x + b4.x, d.y * rstd * g4.y + b4.y,
              d.z * rstd * g4.z + b4.z, d.w * rstd * g4.w + b4.w};
  *(float4*)&x[(size_t)t * E_ + c] = y;
  ushort4 yb = {f2bf(y.x), f2bf(y.y), f2bf(y.z), f2bf(y.w)};
  *(ushort4*)&xb[(size_t)t * E_ + c] = yb;
}

// ---------------- unified weight prep: all transposes + bias concat --------------
__global__ __launch_bounds__(256) void k_prep(
    const float* __restrict__ Wq, const float* __restrict__ Wk,
    const float* __restrict__ Wv, const float* __restrict__ Wo,
    const float* __restrict__ dW1, const float* __restrict__ W1,
    const float* __restrict__ W2, const float* __restrict__ bq,
    const float* __restrict__ bk, const float* __restrict__ bv,
    ushort_t* __restrict__ wqkvT, ushort_t* __restrict__ woT,
    ushort_t* __restrict__ dw1T, ushort_t* __restrict__ w1T,
    ushort_t* __restrict__ w2T, float* __restrict__ bqkv) {
  int z = blockIdx.z;
  if (z == 25) {
    if (blockIdx.x == 0 && blockIdx.y == 0) {
      for (int i = threadIdx.x; i < L_ * 768; i += 256) {
        int l = i / 768, c = i - l * 768;
        float v = (c < 256) ? bq[l * 256 + c]
                : (c < 512) ? bk[l * 256 + c - 256]
                            : bv[l * 256 + c - 512];
        bqkv[i] = v;
      }
    }
    return;
  }
  const float* src;
  ushort_t* dst;
  int K, J;
  if (z < 17) {
    if (blockIdx.x >= 8 || blockIdx.y >= 8) return;
    K = 256; J = 256;
    if (z == 16) { src = dW1; dst = dw1T; }
    else {
      int w = z >> 2, l = z & 3;
      const float* ws = (w == 0) ? Wq : (w == 1) ? Wk : (w == 2) ? Wv : Wo;
      src = ws + (size_t)l * 65536;
      dst = (w < 3) ? (wqkvT + (size_t)l * 768 * 256 + (size_t)w * 256 * 256)
                    : (woT + (size_t)l * 65536);
    }
  } else if (z < 21) {
    int l = z - 17; K = 256; J = 512;
    if (blockIdx.y >= 8) return;
    src = W1 + (size_t)l * K * J; dst = w1T + (size_t)l * J * K;
  } else {
    int l = z - 21; K = 512; J = 256;
    if (blockIdx.x >= 8) return;
    src = W2 + (size_t)l * K * J; dst = w2T + (size_t)l * J * K;
  }
  __shared__ float tile[32][33];
  int j0 = blockIdx.x * 32, k0 = blockIdx.y * 32;
  int tx = threadIdx.x & 31, ty = threadIdx.x >> 5;
  #pragma unroll
  for (int rr = 0; rr < 4; rr++) {
    int kk = ty * 4 + rr;
    tile[kk][tx] = src[(size_t)(k0 + kk) * J + j0 + tx];
  }
  __syncthreads();
  #pragma unroll
  for (int rr = 0; rr < 4; rr++) {
    int jj = ty * 4 + rr;
    dst[(size_t)(j0 + jj) * K + k0 + tx] = f2bf(tile[tx][jj]);
  }
}

// -------- fused QKV + attention: one block per (n, h) ----------------------------
// Stage X in LDS; per-head QKV via MFMA (B from global wqkvT panels, shared across
// blocks of the same h); Q/K/V -> LDS (bias + bf16, same cast point as before);
// QK^T / softmax / PV identical to the old k_attn. P overlays the dead X stage.
__global__ __launch_bounds__(256) void k_qa(
    const ushort_t* __restrict__ xb, const ushort_t* __restrict__ wqkvT_l,
    const float* __restrict__ bqkv_l, ushort_t* __restrict__ o) {
  __shared__ __align__(16) ushort_t xs[64 * 264];  // X stage; P [64][72] overlays
  __shared__ __align__(16) ushort_t qs[64 * 40];
  __shared__ __align__(16) ushort_t ks[64 * 40];
  __shared__ __align__(16) ushort_t vt_[32 * 72];  // V^T [d][t]
  int n = blockIdx.x >> 3, h = blockIdx.x & 7;
  int tid = threadIdx.x, lane = tid & 63, wv = tid >> 6;
  int l15 = lane & 15, l4 = lane >> 4;
  const ushort_t* xsrc = xb + (size_t)n * S_ * E_;
  for (int i = tid; i < 64 * 32; i += 256) {
    int r = i >> 5, c = (i & 31) * 8;
    *(uint4*)&xs[r * 264 + c] = *(const uint4*)&xsrc[(size_t)r * E_ + c];
  }
  __syncthreads();
  // QKV for head h: rows wave-local (wv*16..+16), 32 head cols (st in {0,1})
  const ushort_t* xrow = &xs[(wv * 16 + l15) * 264 + l4 * 8];
  const ushort_t* wq = wqkvT_l + (size_t)(h * 32) * E_ + l4 * 8;
  const ushort_t* wk = wqkvT_l + (size_t)(256 + h * 32) * E_ + l4 * 8;
  const ushort_t* wvp = wqkvT_l + (size_t)(512 + h * 32) * E_ + l4 * 8;
  f32x4 qa[2] = {}, ka[2] = {}, va[2] = {};
  #pragma unroll
  for (int kb = 0; kb < 8; kb++) {
    bf16x8 a = *(const bf16x8*)(xrow + kb * 32);
    #pragma unroll
    for (int st = 0; st < 2; st++) {
      bf16x8 bq_ = *(const bf16x8*)(wq + (size_t)(st * 16 + l15) * E_ + kb * 32);
      bf16x8 bk_ = *(const bf16x8*)(wk + (size_t)(st * 16 + l15) * E_ + kb * 32);
      bf16x8 bv_ = *(const bf16x8*)(wvp + (size_t)(st * 16 + l15) * E_ + kb * 32);
      qa[st] = MFMA16(a, bq_, qa[st]);
      ka[st] = MFMA16(a, bk_, ka[st]);
      va[st] = MFMA16(a, bv_, va[st]);
    }
  }
  // bias + bf16 cast (same rounding point as the old qkv path) -> LDS
  #pragma unroll
  for (int st = 0; st < 2; st++) {
    int c = st * 16 + l15;
    float bqv = bqkv_l[h * 32 + c];
    float bkv = bqkv_l[256 + h * 32 + c];
    float bvv = bqkv_l[512 + h * 32 + c];
    #pragma unroll
    for (int r = 0; r < 4; r++) {
      int t = wv * 16 + l4 * 4 + r;
      qs[t * 40 + c] = f2bf(qa[st][r] + bqv);
      ks[t * 40 + c] = f2bf(ka[st][r] + bkv);
      vt_[c * 72 + t] = f2bf(va[st][r] + bvv);
    }
  }
  __syncthreads();  // covers: ks/vt cross-wave reads below; xs reads done above
  // QK^T
  int srow = wv * 16 + l15;
  bf16x8 aq = *(const bf16x8*)&qs[srow * 40 + l4 * 8];
  f32x4 sc[4];
  #pragma unroll
  for (int st = 0; st < 4; st++) {
    bf16x8 bk_ = *(const bf16x8*)&ks[(st * 16 + l15) * 40 + l4 * 8];
    f32x4 z = {};
    sc[st] = MFMA16(aq, bk_, z);
  }
  const float scale = 0.17677669529663687f;  // 1/sqrt(32)
  #pragma unroll
  for (int st = 0; st < 4; st++)
    #pragma unroll
    for (int r = 0; r < 4; r++) sc[st][r] *= scale;
  ushort_t* ps = xs;  // P [s][t], row stride 72; wave-local rows
  #pragma unroll
  for (int r = 0; r < 4; r++) {
    float m = fmaxf(fmaxf(sc[0][r], sc[1][r]), fmaxf(sc[2][r], sc[3][r]));
    m = fmaxf(m, __shfl_xor(m, 1, 64));
    m = fmaxf(m, __shfl_xor(m, 2, 64));
    m = fmaxf(m, __shfl_xor(m, 4, 64));
    m = fmaxf(m, __shfl_xor(m, 8, 64));
    float p0 = __expf(sc[0][r] - m), p1 = __expf(sc[1][r] - m);
    float p2 = __expf(sc[2][r] - m), p3 = __expf(sc[3][r] - m);
    float sum = p0 + p1 + p2 + p3;
    sum += __shfl_xor(sum, 1, 64);
    sum += __shfl_xor(sum, 2, 64);
    sum += __shfl_xor(sum, 4, 64);
    sum += __shfl_xor(sum, 8, 64);
    float inv = 1.f / sum;
    int prow = (wv * 16 + l4 * 4 + r) * 72;
    ps[prow + 0 * 16 + l15] = f2bf(p0 * inv);
    ps[prow + 1 * 16 + l15] = f2bf(p1 * inv);
    ps[prow + 2 * 16 + l15] = f2bf(p2 * inv);
    ps[prow + 3 * 16 + l15] = f2bf(p3 * inv);
  }
  // PV (ps rows wave-local; vt covered by the barrier above)
  f32x4 oc[2] = {};
  #pragma unroll
  for (int kb = 0; kb < 2; kb++) {
    bf16x8 ap = *(const bf16x8*)&ps[srow * 72 + kb * 32 + l4 * 8];
    #pragma unroll
    for (int st2 = 0; st2 < 2; st2++) {
      bf16x8 bv_ = *(const bf16x8*)&vt_[(st2 * 16 + l15) * 72 + kb * 32 + l4 * 8];
      oc[st2] = MFMA16(ap, bv_, oc[st2]);
    }
  }
  ushort_t* ob = o + (size_t)n * S_ * E_ + h * DH_;
  #pragma unroll
  for (int st2 = 0; st2 < 2; st2++)
    #pragma unroll
    for (int r = 0; r < 4; r++)
      ob[(size_t)(wv * 16 + l4 * 4 + r) * E_ + st2 * 16 + l15] = f2bf(oc[st2][r]);
}

// ------- fused GEMM (Nout=256) + [gelu] + [residual] + LN, 16 rows/block --------
template <int K, int GELU_PRE, int HAS_RES, int OUT_F32>
__global__ __launch_bounds__(256) void k_mm_ln2(
    const ushort_t* __restrict__ Xb, const ushort_t* __restrict__ WT,
    const float* __restrict__ bias, const float* __restrict__ res,
    const float* __restrict__ g, const float* __restrict__ bet,
    float* __restrict__ y, ushort_t* __restrict__ yb) {
  constexpr int STR = K + 8;
  __shared__ ushort_t xs[16 * STR];
  __shared__ float redA[4][16], redB[4][16];
  int tid = threadIdx.x, lane = tid & 63, wv = tid >> 6;
  int t0 = blockIdx.x * 16;
  const ushort_t* xsrc = Xb + (size_t)t0 * K;
  for (int i = tid; i < 16 * (K / 8); i += 256) {
    int r = i / (K / 8), c = (i % (K / 8)) * 8;
    *(uint4*)&xs[r * STR + c] = *(const uint4*)&xsrc[(size_t)r * K + c];
  }
  __syncthreads();
  int l15 = lane & 15, l4 = lane >> 4;
  f32x4 acc[4] = {};
  const ushort_t* xrow = &xs[l15 * STR + l4 * 8];
  const ushort_t* wrow = WT + (size_t)(wv * 64) * K + l4 * 8;
  #pragma unroll
  for (int kb = 0; kb < K / 32; kb++) {
    bf16x8 a = *(const bf16x8*)(xrow + kb * 32);
    #pragma unroll
    for (int st = 0; st < 4; st++) {
      bf16x8 bfr = *(const bf16x8*)(wrow + (size_t)(st * 16 + l15) * K + kb * 32);
      acc[st] = MFMA16(a, bfr, acc[st]);
    }
  }
  float val[4][4];
  #pragma unroll
  for (int st = 0; st < 4; st++) {
    int j = wv * 64 + st * 16 + l15;
    float bv_ = bias[j];
    #pragma unroll
    for (int r = 0; r < 4; r++) {
      float v = acc[st][r] + bv_;
      if (GELU_PRE) v = geluf(v);
      if (HAS_RES) v += res[(size_t)(t0 + l4 * 4 + r) * E_ + j];
      val[st][r] = v;
    }
  }
  #pragma unroll
  for (int r = 0; r < 4; r++) {
    float s = val[0][r] + val[1][r] + val[2][r] + val[3][r];
    s = l15_sum(s);
    if (l15 == 0) redA[wv][l4 * 4 + r] = s;
  }
  __syncthreads();
  float mean[4];
  #pragma unroll
  for (int r = 0; r < 4; r++) {
    int row = l4 * 4 + r;
    mean[r] = (redA[0][row] + redA[1][row] + redA[2][row] + redA[3][row]) * (1.f / E_);
  }
  #pragma unroll
  for (int r = 0; r < 4; r++) {
    float s = 0.f;
    #pragma unroll
    for (int st = 0; st < 4; st++) {
      float d = val[st][r] - mean[r];
      s += d * d;
    }
    s = l15_sum(s);
    if (l15 == 0) redB[wv][l4 * 4 + r] = s;
  }
  __syncthreads();
  float rstd[4];
  #pragma unroll
  for (int r = 0; r < 4; r++) {
    int row = l4 * 4 + r;
    float var = (redB[0][row] + redB[1][row] + redB[2][row] + redB[3][row]) * (1.f / E_);
    rstd[r] = 1.f / sqrtf(var + 1e-5f);
  }
  #pragma unroll
  for (int st = 0; st < 4; st++) {
    int j = wv * 64 + st * 16 + l15;
    float gj = g[j], bj = bet[j];
    #pragma unroll
    for (int r = 0; r < 4; r++) {
      int t = t0 + l4 * 4 + r;
      float o = (val[st][r] - mean[r]) * rstd[r] * gj + bj;
      if (OUT_F32) y[(size_t)t * E_ + j] = o;
      yb[(size_t)t * E_ + j] = f2bf(o);
    }
  }
}

// -------- fused FFN: gelu(X@W1+b1)@W2 + b2 + residual + LN, 16 rows/block -------
__global__ __launch_bounds__(256) void k_ff(
    const ushort_t* __restrict__ Xb, const ushort_t* __restrict__ W1T,
    const float* __restrict__ b1v, const ushort_t* __restrict__ W2T,
    const float* __restrict__ b2v, const float* __restrict__ res,
    const float* __restrict__ g, const float* __restrict__ bet,
    float* __restrict__ y, ushort_t* __restrict__ yb) {
  __shared__ ushort_t xs[16 * 264];
  __shared__ ushort_t hsd[16 * 520];
  __shared__ float redA[4][16], redB[4][16];
  int tid = threadIdx.x, lane = tid & 63, wv = tid >> 6;
  int t0 = blockIdx.x * 16;
  const ushort_t* xsrc = Xb + (size_t)t0 * E_;
  for (int i = tid; i < 16 * 32; i += 256) {
    int r = i >> 5, c = (i & 31) * 8;
    *(uint4*)&xs[r * 264 + c] = *(const uint4*)&xsrc[(size_t)r * E_ + c];
  }
  __syncthreads();
  int l15 = lane & 15, l4 = lane >> 4;
  f32x4 acc1[8] = {};
  const ushort_t* xrow = &xs[l15 * 264 + l4 * 8];
  const ushort_t* w1r = W1T + (size_t)(wv * 128) * E_ + l4 * 8;
  #pragma unroll
  for (int kb = 0; kb < 8; kb++) {
    bf16x8 a = *(const bf16x8*)(xrow + kb * 32);
    #pragma unroll
    for (int ht = 0; ht < 8; ht++) {
      bf16x8 b = *(const bf16x8*)(w1r + (size_t)(ht * 16 + l15) * E_ + kb * 32);
      acc1[ht] = MFMA16(a, b, acc1[ht]);
    }
  }
  #pragma unroll
  for (int ht = 0; ht < 8; ht++) {
    int hc = wv * 128 + ht * 16 + l15;
    float bv_ = b1v[hc];
    #pragma unroll
    for (int r = 0; r < 4; r++) {
      float v = geluf(acc1[ht][r] + bv_);
      hsd[(l4 * 4 + r) * 520 + hc] = f2bf(v);
    }
  }
  __syncthreads();
  f32x4 acc2[4] = {};
  const ushort_t* hrow = &hsd[l15 * 520 + l4 * 8];
  const ushort_t* w2r = W2T + (size_t)(wv * 64) * H_ + l4 * 8;
  #pragma unroll
  for (int kb = 0; kb < 16; kb++) {
    bf16x8 a = *(const bf16x8*)(hrow + kb * 32);
    #pragma unroll
    for (int st = 0; st < 4; st++) {
      bf16x8 b = *(const bf16x8*)(w2r + (size_t)(st * 16 + l15) * H_ + kb * 32);
      acc2[st] = MFMA16(a, b, acc2[st]);
    }
  }
  float val[4][4];
  #pragma unroll
  for (int st = 0; st < 4; st++) {
    int j = wv * 64 + st * 16 + l15;
    float bv_ = b2v[j];
    #pragma unroll
    for (int r = 0; r < 4; r++)
      val[st][r] = acc2[st][r] + bv_ + res[(size_t)(t0 + l4 * 4 + r) * E_ + j];
  }
  #pragma unroll
  for (int r = 0; r < 4; r++) {
    float s = val[0][r] + val[1][r] + val[2][r] + val[3][r];
    s = l15_sum(s);
    if (l15 == 0) redA[wv][l4 * 4 + r] = s;
  }
  __syncthreads();
  float mean[4];
  #pragma unroll
  for (int r = 0; r < 4; r++) {
    int row = l4 * 4 + r;
    mean[r] = (redA[0][row] + redA[1][row] + redA[2][row] + redA[3][row]) * (1.f / E_);
  }
  #pragma unroll
  for (int r = 0; r < 4; r++) {
    float s = 0.f;
    #pragma unroll
    for (int st = 0; st < 4; st++) {
      float d = val[st][r] - mean[r];
      s += d * d;
    }
    s = l15_sum(s);
    if (l15 == 0) redB[wv][l4 * 4 + r] = s;
  }
  __syncthreads();
  float rstd[4];
  #pragma unroll
  for (int r = 0; r < 4; r++) {
    int row = l4 * 4 + r;
    float var = (redB[0][row] + redB[1][row] + redB[2][row] + redB[3][row]) * (1.f / E_);
    rstd[r] = 1.f / sqrtf(var + 1e-5f);
  }
  #pragma unroll
  for (int st = 0; st < 4; st++) {
    int j = wv * 64 + st * 16 + l15;
    float gj = g[j], bj = bet[j];
    #pragma unroll
    for (int r = 0; r < 4; r++) {
      int t = t0 + l4 * 4 + r;
      float o = (val[st][r] - mean[r]) * rstd[r] * gj + bj;
      y[(size_t)t * E_ + j] = o;
      yb[(size_t)t * E_ + j] = f2bf(o);
    }
  }
}

// ---------------- dW2 [E][V] f32 -> wt [VPAD][E] bf16 ----------------
__global__ __launch_bounds__(256) void k_w2t(const float* __restrict__ w,
                                             ushort_t* __restrict__ wt) {
  __shared__ float tile[32 * 33];
  int tx = threadIdx.x & 31, ty = threadIdx.x >> 5;
  int v0 = blockIdx.x * 32, k0 = blockIdx.y * 32;
  #pragma unroll
  for (int rr = 0; rr < 4; rr++) {
    int kk = ty * 4 + rr;
    int vv = v0 + tx;
    tile[kk * 33 + tx] = (vv < V_) ? w[(size_t)(k0 + kk) * V_ + vv] : 0.f;
  }
  __syncthreads();
  #pragma unroll
  for (int rr = 0; rr < 4; rr++) {
    int vv = ty * 4 + rr;
    wt[(size_t)(v0 + vv) * E_ + k0 + tx] = f2bf(tile[tx * 33 + vv]);
  }
}

// ---------------- vocab GEMM: 256v x 64s per block, two 128-v halves -------------
__global__ __launch_bounds__(256) void k_vocab(
    const ushort_t* __restrict__ hbf, const ushort_t* __restrict__ wt,
    const float* __restrict__ db2, float* __restrict__ out,
    float* __restrict__ pmax, float* __restrict__ psum) {
  __shared__ ushort_t hs[64 * 264];
  __shared__ float redm[4][64];
  __shared__ float reds[4][64];
  int n = blockIdx.x, vt = blockIdx.y;
  int tid = threadIdx.x, lane = tid & 63, wv = tid >> 6;
  const ushort_t* hsrc = hbf + (size_t)n * S_ * E_;
  for (int i = tid; i < (S_ * E_) / 8; i += 256) {
    int s = i >> 5, kc = (i & 31) * 8;
    *(uint4*)&hs[s * 264 + kc] = *(const uint4*)&hsrc[s * E_ + kc];
  }
  __syncthreads();
  int l15 = lane & 15, l4 = lane >> 4;
  float rm[4], rs[4];
  #pragma unroll
  for (int st = 0; st < 4; st++) { rm[st] = -INFINITY; rs[st] = 0.f; }
  #pragma unroll
  for (int h2 = 0; h2 < 2; h2++) {
    const ushort_t* Ap0 =
        wt + (size_t)(vt * 256 + h2 * 128 + wv * 16 + l15) * E_ + l4 * 8;
    const ushort_t* Ap1 = Ap0 + (size_t)64 * E_;
    f32x4 acc[2][4] = {};
    #pragma unroll
    for (int kb = 0; kb < 8; kb++) {
      bf16x8 a0 = *(const bf16x8*)(Ap0 + kb * 32);
      bf16x8 a1 = *(const bf16x8*)(Ap1 + kb * 32);
      #pragma unroll
      for (int st = 0; st < 4; st++) {
        bf16x8 bfr = *(const bf16x8*)&hs[(st * 16 + l15) * 264 + kb * 32 + l4 * 8];
        acc[0][st] = MFMA16(a0, bfr, acc[0][st]);
        acc[1][st] = MFMA16(a1, bfr, acc[1][st]);
      }
    }
    float vals[2][4][4];
    #pragma unroll
    for (int mt = 0; mt < 2; mt++) {
      #pragma unroll
      for (int j = 0; j < 4; j++) {
        int v = vt * 256 + h2 * 128 + wv * 16 + mt * 64 + l4 * 4 + j;
        bool valid = v < V_;
        float bias = valid ? db2[v] : 0.f;
        size_t ob = ((size_t)n * V_ + v) * S_;
        #pragma unroll
        for (int st = 0; st < 4; st++) {
          float val = valid ? (acc[mt][st][j] + bias) : -INFINITY;
          vals[mt][st][j] = val;
          if (valid) __builtin_nontemporal_store(val, &out[ob + st * 16 + l15]);
        }
      }
    }
    #pragma unroll
    for (int st = 0; st < 4; st++) {
      float m = -INFINITY;
      #pragma unroll
      for (int mt = 0; mt < 2; mt++)
        #pragma unroll
        for (int j = 0; j < 4; j++) m = fmaxf(m, vals[mt][st][j]);
      m = fmaxf(m, __shfl_xor(m, 16, 64));
      m = fmaxf(m, __shfl_xor(m, 32, 64));
      float sum = 0.f;
      #pragma unroll
      for (int mt = 0; mt < 2; mt++)
        #pragma unroll
        for (int j = 0; j < 4; j++) sum += __expf(vals[mt][st][j] - m);
      sum += __shfl_xor(sum, 16, 64);
      sum += __shfl_xor(sum, 32, 64);
      float nm = fmaxf(rm[st], m);
      rs[st] = rs[st] * __expf(rm[st] - nm) + sum * __expf(m - nm);
      rm[st] = nm;
    }
  }
  if (l4 == 0) {
    #pragma unroll
    for (int st = 0; st < 4; st++) {
      redm[wv][st * 16 + l15] = rm[st];
      reds[wv][st * 16 + l15] = rs[st];
    }
  }
  __syncthreads();
  if (wv == 0 && l4 == 0) {
    #pragma unroll
    for (int st = 0; st < 4; st++) {
      int s = st * 16 + l15;
      float M = fmaxf(fmaxf(redm[0][s], redm[1][s]), fmaxf(redm[2][s], redm[3][s]));
      float Sa = reds[0][s] * __expf(redm[0][s] - M) +
                 reds[1][s] * __expf(redm[1][s] - M) +
                 reds[2][s] * __expf(redm[2][s] - M) +
                 reds[3][s] * __expf(redm[3][s] - M);
      size_t pi = ((size_t)n * NVT_ + vt) * S_ + s;
      pmax[pi] = M;
      psum[pi] = Sa;
    }
  }
}

// ---------------- loss finalize (512 threads) ----------------
__global__ __launch_bounds__(512) void k_lossf(
    const float* __restrict__ pmax, const float* __restrict__ psum,
    const float* __restrict__ out, const int* __restrict__ label,
    float* __restrict__ partial) {
  __shared__ float sm[512], ssum[512];
  int n = blockIdx.x, tid = threadIdx.x;
  int s = tid & 63, qq = tid >> 6;  // qq in [0,8)
  float m = -INFINITY, sum = 0.f;
  for (int vt = qq; vt < NVT_; vt += 8) {
    size_t pi = ((size_t)n * NVT_ + vt) * S_ + s;
    float m2 = pmax[pi], s2 = psum[pi];
    float nm = fmaxf(m, m2);
    sum = sum * __expf(m - nm) + s2 * __expf(m2 - nm);
    m = nm;
  }
  sm[tid] = m; ssum[tid] = sum;
  __syncthreads();
  if (qq == 0) {
    float M = sm[s], Sa = ssum[s];
    #pragma unroll
    for (int p = 1; p < 8; p++) {
      float m2 = sm[p * 64 + s], s2 = ssum[p * 64 + s];
      float nm = fmaxf(M, m2);
      Sa = Sa * __expf(M - nm) + s2 * __expf(m2 - nm);
      M = nm;
    }
    float lse = M + logf(Sa);
    int lab = label[n * S_ + s];
    float lx = out[((size_t)n * V_ + lab) * S_ + s];
    partial[n * S_ + s] = lse - lx;
  }
}

__global__ __launch_bounds__(256) void k_loss2(const float* __restrict__ partial,
                                               float* __restrict__ dst) {
  __shared__ float sbuf[4];
  int tid = threadIdx.x;
  float acc = 0.f;
  for (int i = tid; i < T_; i += 256) acc += partial[i];
  #pragma unroll
  for (int off = 32; off >= 1; off >>= 1) acc += __shfl_xor(acc, off, 64);
  int lane = tid & 63, wid = tid >> 6;
  if (lane == 0) sbuf[wid] = acc;
  __syncthreads();
  if (tid == 0) dst[0] = (sbuf[0] + sbuf[1] + sbuf[2] + sbuf[3]) / (float)T_;
}

extern "C" void kernel_launch(void* const* d_in, const int* in_sizes, int n_in,
                              void* d_out, int out_size, void* d_ws, size_t ws_size,
                              hipStream_t stream) {
  const int*   label = (const int*)d_in[0];
  const int*   mask  = (const int*)d_in[1];
  const float* emb   = (const float*)d_in[2];
  const float* pos   = (const float*)d_in[3];
  const float* emb_g = (const float*)d_in[4];
  const float* emb_b = (const float*)d_in[5];
  const float* Wq  = (const float*)d_in[6];
  const float* bq  = (const float*)d_in[7];
  const float* Wk  = (const float*)d_in[8];
  const float* bk  = (const float*)d_in[9];
  const float* Wv  = (const float*)d_in[10];
  const float* bv  = (const float*)d_in[11];
  const float* Wo  = (const float*)d_in[12];
  const float* bo  = (const float*)d_in[13];
  const float* n1g = (const float*)d_in[14];
  const float* n1b = (const float*)d_in[15];
  const float* W1  = (const float*)d_in[16];
  const float* b1  = (const float*)d_in[17];
  const float* W2  = (const float*)d_in[18];
  const float* b2  = (const float*)d_in[19];
  const float* n2g = (const float*)d_in[20];
  const float* n2b = (const float*)d_in[21];
  const float* dW1 = (const float*)d_in[22];
  const float* db1 = (const float*)d_in[23];
  const float* dng = (const float*)d_in[24];
  const float* dnb = (const float*)d_in[25];
  const float* dW2 = (const float*)d_in[26];
  const float* db2 = (const float*)d_in[27];
  float* out = (float*)d_out;
  (void)in_sizes; (void)n_in; (void)out_size; (void)ws_size;

  char* base = (char*)d_ws;
  size_t off = 0;
  auto alloc = [&](size_t bytes) {
    char* p = base + off;
    off += (bytes + 255) & ~(size_t)255;
    return p;
  };
  float*    x    = (float*)alloc((size_t)T_ * E_ * 4);
  ushort_t* xb   = (ushort_t*)alloc((size_t)T_ * E_ * 2);
  float*    x1   = (float*)alloc((size_t)T_ * E_ * 4);
  ushort_t* x1b  = (ushort_t*)alloc((size_t)T_ * E_ * 2);
  ushort_t* obuf = (ushort_t*)alloc((size_t)T_ * E_ * 2);
  ushort_t* wqkvT = (ushort_t*)alloc((size_t)L_ * 768 * E_ * 2);
  ushort_t* woT   = (ushort_t*)alloc((size_t)L_ * E_ * E_ * 2);
  ushort_t* w1T   = (ushort_t*)alloc((size_t)L_ * H_ * E_ * 2);
  ushort_t* w2T   = (ushort_t*)alloc((size_t)L_ * E_ * H_ * 2);
  ushort_t* dw1T  = (ushort_t*)alloc((size_t)E_ * E_ * 2);
  ushort_t* wt    = (ushort_t*)alloc((size_t)VPAD_ * E_ * 2);
  float*    bqkv  = (float*)alloc((size_t)L_ * 768 * 4);
  float*    partial = (float*)alloc((size_t)T_ * 4);
  ushort_t* hbf = obuf;       // alias: obuf dead after the loop
  float* pmax = x;            // alias: x/x1 span dead by k_vocab (~8.6 MB needed)
  float* psum = pmax + (size_t)N_ * NVT_ * S_;

  // ---- one-time weight prep (2 launches) ----
  k_prep<<<dim3(16, 16, 26), 256, 0, stream>>>(Wq, Wk, Wv, Wo, dW1, W1, W2,
                                               bq, bk, bv, wqkvT, woT, dw1T,
                                               w1T, w2T, bqkv);
  k_w2t<<<dim3(VPAD_ / 32, E_ / 32), 256, 0, stream>>>(dW2, wt);

  k_embed_ln<<<T_ / 4, 256, 0, stream>>>(label, mask, emb, pos, emb_g, emb_b, x, xb);

  for (int l = 0; l < L_; l++) {
    // fused QKV + attention -> obuf (bf16)
    k_qa<<<N_ * NH_, 256, 0, stream>>>(
        xb, wqkvT + (size_t)l * 768 * E_, bqkv + l * 768, obuf);
    // Wo + residual(x) + LN1 -> x1 (f32) + x1b (bf16)
    k_mm_ln2<E_, 0, 1, 1><<<T_ / 16, 256, 0, stream>>>(
        obuf, woT + (size_t)l * E_ * E_, bo + l * E_, x,
        n1g + l * E_, n1b + l * E_, x1, x1b);
    // fused FFN + residual(x1) + LN2 -> x (f32) + xb (bf16)
    k_ff<<<T_ / 16, 256, 0, stream>>>(
        x1b, w1T + (size_t)l * H_ * E_, b1 + l * H_,
        w2T + (size_t)l * E_ * H_, b2 + l * E_, x1,
        n2g + l * E_, n2b + l * E_, x, xb);
  }

  // decoder head: LN(gelu(x @ dW1 + db1)) -> hbf (bf16)
  k_mm_ln2<E_, 1, 0, 0><<<T_ / 16, 256, 0, stream>>>(
      xb, dw1T, db1, nullptr, dng, dnb, nullptr, hbf);

  // vocab projection + transposed store + fused softmax partials
  k_vocab<<<dim3(N_, NVT_), 256, 0, stream>>>(hbf, wt, db2, out, pmax, psum);

  // loss
  k_lossf<<<N_, 512, 0, stream>>>(pmax, psum, out, label, partial);
  k_loss2<<<1, 256, 0, stream>>>(partial, out + (size_t)N_ * V_ * S_);
}

// Round 10
// 809.502 us; speedup vs baseline: 1.4758x; 1.0221x over previous
//
#include <hip/hip_runtime.h>
#include <hip/hip_bf16.h>

#define DEVFN static __device__ __forceinline__
#define MFMA16(a, b, c) __builtin_amdgcn_mfma_f32_16x16x32_bf16((a), (b), (c), 0, 0, 0)

constexpr int N_ = 128, S_ = 64, T_ = N_ * S_;
constexpr int E_ = 256, H_ = 512, NH_ = 8, DH_ = 32, L_ = 4;
constexpr int V_ = 33279, VPAD_ = 33280, NVT_ = VPAD_ / 256;  // 130 v-tiles of 256

typedef __attribute__((ext_vector_type(8))) short bf16x8;
typedef __attribute__((ext_vector_type(4))) float f32x4;
typedef unsigned short ushort_t;

DEVFN ushort_t f2bf(float f) {
  unsigned int u = __float_as_uint(f);
  unsigned int r = (u + 0x7fffu + ((u >> 16) & 1u)) >> 16;
  return (ushort_t)r;
}
DEVFN float bf2f(ushort_t u) { return __uint_as_float(((unsigned)u) << 16); }

DEVFN float geluf(float x) {
  return 0.5f * x * (1.f + erff(x * 0.70710678118654752440f));
}

DEVFN float wave_sum(float v) {
  #pragma unroll
  for (int off = 32; off >= 1; off >>= 1) v += __shfl_xor(v, off, 64);
  return v;
}

DEVFN float l15_sum(float v) {
  v += __shfl_xor(v, 1, 64);
  v += __shfl_xor(v, 2, 64);
  v += __shfl_xor(v, 4, 64);
  v += __shfl_xor(v, 8, 64);
  return v;
}

// ---------------- embedding + LN: one wave per token row ----------------
__global__ __launch_bounds__(256) void k_embed_ln(
    const int* __restrict__ label, const int* __restrict__ mask,
    const float* __restrict__ emb, const float* __restrict__ pos,
    const float* __restrict__ g, const float* __restrict__ b,
    float* __restrict__ x, ushort_t* __restrict__ xb) {
  int wv = threadIdx.x >> 6, lane = threadIdx.x & 63;
  int t = blockIdx.x * 4 + wv;
  int s = t & (S_ - 1);
  int id = (mask[t] == 1) ? V_ : label[t];
  int c = lane * 4;
  float4 v = *(const float4*)&emb[(size_t)id * E_ + c];
  float4 p = *(const float4*)&pos[s * E_ + c];
  v.x += p.x; v.y += p.y; v.z += p.z; v.w += p.w;
  float mean = wave_sum(v.x + v.y + v.z + v.w) * (1.f / E_);
  float4 d = {v.x - mean, v.y - mean, v.z - mean, v.w - mean};
  float var = wave_sum(d.x * d.x + d.y * d.y + d.z * d.z + d.w * d.w) * (1.f / E_);
  float rstd = 1.f / sqrtf(var + 1e-5f);
  float4 g4 = *(const float4*)&g[c];
  float4 b4 = *(const float4*)&b[c];
  float4 y = {d.x * rstd * g4.x + b4.x, d.y * rstd * g4.y + b4.y,
              d.z * rstd * g4.z + b4.z, d.w * rstd * g4.w + b4.w};
  *(float4*)&x[(size_t)t * E_ + c] = y;
  ushort4 yb = {f2bf(y.x), f2bf(y.y), f2bf(y.z), f2bf(y.w)};
  *(ushort4*)&xb[(size_t)t * E_ + c] = yb;
}

// ---------------- unified weight prep: all transposes + bias concat --------------
__global__ __launch_bounds__(256) void k_prep(
    const float* __restrict__ Wq, const float* __restrict__ Wk,
    const float* __restrict__ Wv, const float* __restrict__ Wo,
    const float* __restrict__ dW1, const float* __restrict__ W1,
    const float* __restrict__ W2, const float* __restrict__ bq,
    const float* __restrict__ bk, const float* __restrict__ bv,
    ushort_t* __restrict__ wqkvT, ushort_t* __restrict__ woT,
    ushort_t* __restrict__ dw1T, ushort_t* __restrict__ w1T,
    ushort_t* __restrict__ w2T, float* __restrict__ bqkv) {
  int z = blockIdx.z;
  if (z == 25) {
    if (blockIdx.x == 0 && blockIdx.y == 0) {
      for (int i = threadIdx.x; i < L_ * 768; i += 256) {
        int l = i / 768, c = i - l * 768;
        float v = (c < 256) ? bq[l * 256 + c]
                : (c < 512) ? bk[l * 256 + c - 256]
                            : bv[l * 256 + c - 512];
        bqkv[i] = v;
      }
    }
    return;
  }
  const float* src;
  ushort_t* dst;
  int K, J;
  if (z < 17) {
    if (blockIdx.x >= 8 || blockIdx.y >= 8) return;
    K = 256; J = 256;
    if (z == 16) { src = dW1; dst = dw1T; }
    else {
      int w = z >> 2, l = z & 3;
      const float* ws = (w == 0) ? Wq : (w == 1) ? Wk : (w == 2) ? Wv : Wo;
      src = ws + (size_t)l * 65536;
      dst = (w < 3) ? (wqkvT + (size_t)l * 768 * 256 + (size_t)w * 256 * 256)
                    : (woT + (size_t)l * 65536);
    }
  } else if (z < 21) {
    int l = z - 17; K = 256; J = 512;
    if (blockIdx.y >= 8) return;
    src = W1 + (size_t)l * K * J; dst = w1T + (size_t)l * J * K;
  } else {
    int l = z - 21; K = 512; J = 256;
    if (blockIdx.x >= 8) return;
    src = W2 + (size_t)l * K * J; dst = w2T + (size_t)l * J * K;
  }
  __shared__ float tile[32][33];
  int j0 = blockIdx.x * 32, k0 = blockIdx.y * 32;
  int tx = threadIdx.x & 31, ty = threadIdx.x >> 5;
  #pragma unroll
  for (int rr = 0; rr < 4; rr++) {
    int kk = ty * 4 + rr;
    tile[kk][tx] = src[(size_t)(k0 + kk) * J + j0 + tx];
  }
  __syncthreads();
  #pragma unroll
  for (int rr = 0; rr < 4; rr++) {
    int jj = ty * 4 + rr;
    dst[(size_t)(j0 + jj) * K + k0 + tx] = f2bf(tile[tx][jj]);
  }
}

// -------- fused QKV + attention: one block per (n, h) ----------------------------
__global__ __launch_bounds__(256) void k_qa(
    const ushort_t* __restrict__ xb, const ushort_t* __restrict__ wqkvT_l,
    const float* __restrict__ bqkv_l, ushort_t* __restrict__ o) {
  __shared__ __align__(16) ushort_t xs[64 * 264];  // X stage; P [64][72] overlays
  __shared__ __align__(16) ushort_t qs[64 * 40];
  __shared__ __align__(16) ushort_t ks[64 * 40];
  __shared__ __align__(16) ushort_t vt_[32 * 72];  // V^T [d][t]
  int n = blockIdx.x >> 3, h = blockIdx.x & 7;
  int tid = threadIdx.x, lane = tid & 63, wv = tid >> 6;
  int l15 = lane & 15, l4 = lane >> 4;
  const ushort_t* xsrc = xb + (size_t)n * S_ * E_;
  for (int i = tid; i < 64 * 32; i += 256) {
    int r = i >> 5, c = (i & 31) * 8;
    *(uint4*)&xs[r * 264 + c] = *(const uint4*)&xsrc[(size_t)r * E_ + c];
  }
  __syncthreads();
  const ushort_t* xrow = &xs[(wv * 16 + l15) * 264 + l4 * 8];
  const ushort_t* wq = wqkvT_l + (size_t)(h * 32) * E_ + l4 * 8;
  const ushort_t* wk = wqkvT_l + (size_t)(256 + h * 32) * E_ + l4 * 8;
  const ushort_t* wvp = wqkvT_l + (size_t)(512 + h * 32) * E_ + l4 * 8;
  f32x4 qa[2] = {}, ka[2] = {}, va[2] = {};
  #pragma unroll
  for (int kb = 0; kb < 8; kb++) {
    bf16x8 a = *(const bf16x8*)(xrow + kb * 32);
    #pragma unroll
    for (int st = 0; st < 2; st++) {
      bf16x8 bq_ = *(const bf16x8*)(wq + (size_t)(st * 16 + l15) * E_ + kb * 32);
      bf16x8 bk_ = *(const bf16x8*)(wk + (size_t)(st * 16 + l15) * E_ + kb * 32);
      bf16x8 bv_ = *(const bf16x8*)(wvp + (size_t)(st * 16 + l15) * E_ + kb * 32);
      qa[st] = MFMA16(a, bq_, qa[st]);
      ka[st] = MFMA16(a, bk_, ka[st]);
      va[st] = MFMA16(a, bv_, va[st]);
    }
  }
  #pragma unroll
  for (int st = 0; st < 2; st++) {
    int c = st * 16 + l15;
    float bqv = bqkv_l[h * 32 + c];
    float bkv = bqkv_l[256 + h * 32 + c];
    float bvv = bqkv_l[512 + h * 32 + c];
    #pragma unroll
    for (int r = 0; r < 4; r++) {
      int t = wv * 16 + l4 * 4 + r;
      qs[t * 40 + c] = f2bf(qa[st][r] + bqv);
      ks[t * 40 + c] = f2bf(ka[st][r] + bkv);
      vt_[c * 72 + t] = f2bf(va[st][r] + bvv);
    }
  }
  __syncthreads();
  int srow = wv * 16 + l15;
  bf16x8 aq = *(const bf16x8*)&qs[srow * 40 + l4 * 8];
  f32x4 sc[4];
  #pragma unroll
  for (int st = 0; st < 4; st++) {
    bf16x8 bk_ = *(const bf16x8*)&ks[(st * 16 + l15) * 40 + l4 * 8];
    f32x4 z = {};
    sc[st] = MFMA16(aq, bk_, z);
  }
  const float scale = 0.17677669529663687f;  // 1/sqrt(32)
  #pragma unroll
  for (int st = 0; st < 4; st++)
    #pragma unroll
    for (int r = 0; r < 4; r++) sc[st][r] *= scale;
  ushort_t* ps = xs;
  #pragma unroll
  for (int r = 0; r < 4; r++) {
    float m = fmaxf(fmaxf(sc[0][r], sc[1][r]), fmaxf(sc[2][r], sc[3][r]));
    m = fmaxf(m, __shfl_xor(m, 1, 64));
    m = fmaxf(m, __shfl_xor(m, 2, 64));
    m = fmaxf(m, __shfl_xor(m, 4, 64));
    m = fmaxf(m, __shfl_xor(m, 8, 64));
    float p0 = __expf(sc[0][r] - m), p1 = __expf(sc[1][r] - m);
    float p2 = __expf(sc[2][r] - m), p3 = __expf(sc[3][r] - m);
    float sum = p0 + p1 + p2 + p3;
    sum += __shfl_xor(sum, 1, 64);
    sum += __shfl_xor(sum, 2, 64);
    sum += __shfl_xor(sum, 4, 64);
    sum += __shfl_xor(sum, 8, 64);
    float inv = 1.f / sum;
    int prow = (wv * 16 + l4 * 4 + r) * 72;
    ps[prow + 0 * 16 + l15] = f2bf(p0 * inv);
    ps[prow + 1 * 16 + l15] = f2bf(p1 * inv);
    ps[prow + 2 * 16 + l15] = f2bf(p2 * inv);
    ps[prow + 3 * 16 + l15] = f2bf(p3 * inv);
  }
  f32x4 oc[2] = {};
  #pragma unroll
  for (int kb = 0; kb < 2; kb++) {
    bf16x8 ap = *(const bf16x8*)&ps[srow * 72 + kb * 32 + l4 * 8];
    #pragma unroll
    for (int st2 = 0; st2 < 2; st2++) {
      bf16x8 bv_ = *(const bf16x8*)&vt_[(st2 * 16 + l15) * 72 + kb * 32 + l4 * 8];
      oc[st2] = MFMA16(ap, bv_, oc[st2]);
    }
  }
  ushort_t* ob = o + (size_t)n * S_ * E_ + h * DH_;
  #pragma unroll
  for (int st2 = 0; st2 < 2; st2++)
    #pragma unroll
    for (int r = 0; r < 4; r++)
      ob[(size_t)(wv * 16 + l4 * 4 + r) * E_ + st2 * 16 + l15] = f2bf(oc[st2][r]);
}

// ------- fused GEMM (Nout=256) + [gelu] + LN, 16 rows/block (decoder head) ------
template <int K, int GELU_PRE>
__global__ __launch_bounds__(256) void k_mm_ln2(
    const ushort_t* __restrict__ Xb, const ushort_t* __restrict__ WT,
    const float* __restrict__ bias, const float* __restrict__ g,
    const float* __restrict__ bet, ushort_t* __restrict__ yb) {
  constexpr int STR = K + 8;
  __shared__ ushort_t xs[16 * STR];
  __shared__ float redA[4][16], redB[4][16];
  int tid = threadIdx.x, lane = tid & 63, wv = tid >> 6;
  int t0 = blockIdx.x * 16;
  const ushort_t* xsrc = Xb + (size_t)t0 * K;
  for (int i = tid; i < 16 * (K / 8); i += 256) {
    int r = i / (K / 8), c = (i % (K / 8)) * 8;
    *(uint4*)&xs[r * STR + c] = *(const uint4*)&xsrc[(size_t)r * K + c];
  }
  __syncthreads();
  int l15 = lane & 15, l4 = lane >> 4;
  f32x4 acc[4] = {};
  const ushort_t* xrow = &xs[l15 * STR + l4 * 8];
  const ushort_t* wrow = WT + (size_t)(wv * 64) * K + l4 * 8;
  #pragma unroll
  for (int kb = 0; kb < K / 32; kb++) {
    bf16x8 a = *(const bf16x8*)(xrow + kb * 32);
    #pragma unroll
    for (int st = 0; st < 4; st++) {
      bf16x8 bfr = *(const bf16x8*)(wrow + (size_t)(st * 16 + l15) * K + kb * 32);
      acc[st] = MFMA16(a, bfr, acc[st]);
    }
  }
  float val[4][4];
  #pragma unroll
  for (int st = 0; st < 4; st++) {
    int j = wv * 64 + st * 16 + l15;
    float bv_ = bias[j];
    #pragma unroll
    for (int r = 0; r < 4; r++) {
      float v = acc[st][r] + bv_;
      if (GELU_PRE) v = geluf(v);
      val[st][r] = v;
    }
  }
  #pragma unroll
  for (int r = 0; r < 4; r++) {
    float s = val[0][r] + val[1][r] + val[2][r] + val[3][r];
    s = l15_sum(s);
    if (l15 == 0) redA[wv][l4 * 4 + r] = s;
  }
  __syncthreads();
  float mean[4];
  #pragma unroll
  for (int r = 0; r < 4; r++) {
    int row = l4 * 4 + r;
    mean[r] = (redA[0][row] + redA[1][row] + redA[2][row] + redA[3][row]) * (1.f / E_);
  }
  #pragma unroll
  for (int r = 0; r < 4; r++) {
    float s = 0.f;
    #pragma unroll
    for (int st = 0; st < 4; st++) {
      float d = val[st][r] - mean[r];
      s += d * d;
    }
    s = l15_sum(s);
    if (l15 == 0) redB[wv][l4 * 4 + r] = s;
  }
  __syncthreads();
  float rstd[4];
  #pragma unroll
  for (int r = 0; r < 4; r++) {
    int row = l4 * 4 + r;
    float var = (redB[0][row] + redB[1][row] + redB[2][row] + redB[3][row]) * (1.f / E_);
    rstd[r] = 1.f / sqrtf(var + 1e-5f);
  }
  #pragma unroll
  for (int st = 0; st < 4; st++) {
    int j = wv * 64 + st * 16 + l15;
    float gj = g[j], bj = bet[j];
    #pragma unroll
    for (int r = 0; r < 4; r++) {
      int t = t0 + l4 * 4 + r;
      yb[(size_t)t * E_ + j] = f2bf((val[st][r] - mean[r]) * rstd[r] * gj + bj);
    }
  }
}

// ---- fused attn-out + FFN: Wo+res+LN1 + FF1(gelu)+FF2+res+LN2, 16 rows/block ---
// 4 waves; LN via cross-wave LDS reduce; LN1 f32 kept in regs (FF2 residual),
// LN1 bf16 reuses the obuf-stage LDS for FF1's A operand.
__global__ __launch_bounds__(256) void k_aof(
    const ushort_t* __restrict__ obuf, const ushort_t* __restrict__ woT_l,
    const float* __restrict__ bo_l, const float* __restrict__ xres,
    const float* __restrict__ g1, const float* __restrict__ b1n,
    const ushort_t* __restrict__ w1T_l, const float* __restrict__ b1v,
    const ushort_t* __restrict__ w2T_l, const float* __restrict__ b2v,
    const float* __restrict__ g2, const float* __restrict__ b2n,
    float* __restrict__ yout, ushort_t* __restrict__ ybout) {
  __shared__ ushort_t xs[16 * 264];   // obuf stage, then LN1-bf16 tile
  __shared__ ushort_t hsd[16 * 520];  // FF1 hidden tile
  __shared__ float redA[4][16], redB[4][16];
  int tid = threadIdx.x, lane = tid & 63, wv = tid >> 6;
  int t0 = blockIdx.x * 16;
  int l15 = lane & 15, l4 = lane >> 4;
  const ushort_t* osrc = obuf + (size_t)t0 * E_;
  for (int i = tid; i < 16 * 32; i += 256) {
    int r = i >> 5, c = (i & 31) * 8;
    *(uint4*)&xs[r * 264 + c] = *(const uint4*)&osrc[(size_t)r * E_ + c];
  }
  __syncthreads();
  // ---- Wo GEMM (K=256): cols j = wv*64 + st*16 + l15, rows t0 + l4*4 + r
  f32x4 acc[4] = {};
  {
    const ushort_t* xrow = &xs[l15 * 264 + l4 * 8];
    const ushort_t* wrow = woT_l + (size_t)(wv * 64) * E_ + l4 * 8;
    #pragma unroll
    for (int kb = 0; kb < 8; kb++) {
      bf16x8 a = *(const bf16x8*)(xrow + kb * 32);
      #pragma unroll
      for (int st = 0; st < 4; st++) {
        bf16x8 b = *(const bf16x8*)(wrow + (size_t)(st * 16 + l15) * E_ + kb * 32);
        acc[st] = MFMA16(a, b, acc[st]);
      }
    }
  }
  float val[4][4];
  #pragma unroll
  for (int st = 0; st < 4; st++) {
    int j = wv * 64 + st * 16 + l15;
    float bv_ = bo_l[j];
    #pragma unroll
    for (int r = 0; r < 4; r++)
      val[st][r] = acc[st][r] + bv_ + xres[(size_t)(t0 + l4 * 4 + r) * E_ + j];
  }
  // ---- LN1 (2 barriers)
  #pragma unroll
  for (int r = 0; r < 4; r++) {
    float s = l15_sum(val[0][r] + val[1][r] + val[2][r] + val[3][r]);
    if (l15 == 0) redA[wv][l4 * 4 + r] = s;
  }
  __syncthreads();
  float mean[4];
  #pragma unroll
  for (int r = 0; r < 4; r++) {
    int row = l4 * 4 + r;
    mean[r] = (redA[0][row] + redA[1][row] + redA[2][row] + redA[3][row]) * (1.f / E_);
  }
  #pragma unroll
  for (int r = 0; r < 4; r++) {
    float s = 0.f;
    #pragma unroll
    for (int st = 0; st < 4; st++) {
      float d = val[st][r] - mean[r];
      s += d * d;
    }
    s = l15_sum(s);
    if (l15 == 0) redB[wv][l4 * 4 + r] = s;
  }
  __syncthreads();
  #pragma unroll
  for (int r = 0; r < 4; r++) {
    int row = l4 * 4 + r;
    float var = (redB[0][row] + redB[1][row] + redB[2][row] + redB[3][row]) * (1.f / E_);
    float rstd = 1.f / sqrtf(var + 1e-5f);
    #pragma unroll
    for (int st = 0; st < 4; st++) {
      int j = wv * 64 + st * 16 + l15;
      val[st][r] = (val[st][r] - mean[r]) * rstd * g1[j] + b1n[j];  // x1 (f32, regs)
    }
  }
  // ---- LN1 bf16 -> xs (overwrite; Wo reads finished before LN barriers)
  #pragma unroll
  for (int st = 0; st < 4; st++) {
    int j = wv * 64 + st * 16 + l15;
    #pragma unroll
    for (int r = 0; r < 4; r++)
      xs[(l4 * 4 + r) * 264 + j] = f2bf(val[st][r]);
  }
  __syncthreads();
  // ---- FF1 (K=256): hidden col hc = wv*128 + ht*16 + l15
  f32x4 acc1[8] = {};
  {
    const ushort_t* xrow = &xs[l15 * 264 + l4 * 8];
    const ushort_t* w1r = w1T_l + (size_t)(wv * 128) * E_ + l4 * 8;
    #pragma unroll
    for (int kb = 0; kb < 8; kb++) {
      bf16x8 a = *(const bf16x8*)(xrow + kb * 32);
      #pragma unroll
      for (int ht = 0; ht < 8; ht++) {
        bf16x8 b = *(const bf16x8*)(w1r + (size_t)(ht * 16 + l15) * E_ + kb * 32);
        acc1[ht] = MFMA16(a, b, acc1[ht]);
      }
    }
  }
  #pragma unroll
  for (int ht = 0; ht < 8; ht++) {
    int hc = wv * 128 + ht * 16 + l15;
    float bv_ = b1v[hc];
    #pragma unroll
    for (int r = 0; r < 4; r++)
      hsd[(l4 * 4 + r) * 520 + hc] = f2bf(geluf(acc1[ht][r] + bv_));
  }
  __syncthreads();
  // ---- FF2 (K=512): out col j = wv*64 + st*16 + l15; residual = val (x1)
  f32x4 acc2[4] = {};
  {
    const ushort_t* hrow = &hsd[l15 * 520 + l4 * 8];
    const ushort_t* w2r = w2T_l + (size_t)(wv * 64) * H_ + l4 * 8;
    #pragma unroll
    for (int kb = 0; kb < 16; kb++) {
      bf16x8 a = *(const bf16x8*)(hrow + kb * 32);
      #pragma unroll
      for (int st = 0; st < 4; st++) {
        bf16x8 b = *(const bf16x8*)(w2r + (size_t)(st * 16 + l15) * H_ + kb * 32);
        acc2[st] = MFMA16(a, b, acc2[st]);
      }
    }
  }
  #pragma unroll
  for (int st = 0; st < 4; st++) {
    int j = wv * 64 + st * 16 + l15;
    float bv_ = b2v[j];
    #pragma unroll
    for (int r = 0; r < 4; r++)
      val[st][r] += acc2[st][r] + bv_;  // x1 + FF2(x1)
  }
  // ---- LN2 (2 barriers)
  #pragma unroll
  for (int r = 0; r < 4; r++) {
    float s = l15_sum(val[0][r] + val[1][r] + val[2][r] + val[3][r]);
    if (l15 == 0) redA[wv][l4 * 4 + r] = s;
  }
  __syncthreads();
  #pragma unroll
  for (int r = 0; r < 4; r++) {
    int row = l4 * 4 + r;
    mean[r] = (redA[0][row] + redA[1][row] + redA[2][row] + redA[3][row]) * (1.f / E_);
  }
  #pragma unroll
  for (int r = 0; r < 4; r++) {
    float s = 0.f;
    #pragma unroll
    for (int st = 0; st < 4; st++) {
      float d = val[st][r] - mean[r];
      s += d * d;
    }
    s = l15_sum(s);
    if (l15 == 0) redB[wv][l4 * 4 + r] = s;
  }
  __syncthreads();
  #pragma unroll
  for (int r = 0; r < 4; r++) {
    int row = l4 * 4 + r;
    float var = (redB[0][row] + redB[1][row] + redB[2][row] + redB[3][row]) * (1.f / E_);
    float rstd = 1.f / sqrtf(var + 1e-5f);
    int t = t0 + l4 * 4 + r;
    #pragma unroll
    for (int st = 0; st < 4; st++) {
      int j = wv * 64 + st * 16 + l15;
      float o = (val[st][r] - mean[r]) * rstd * g2[j] + b2n[j];
      if (yout) yout[(size_t)t * E_ + j] = o;
      ybout[(size_t)t * E_ + j] = f2bf(o);
    }
  }
}

// ---------------- dW2 [E][V] f32 -> wt [VPAD][E] bf16 ----------------
__global__ __launch_bounds__(256) void k_w2t(const float* __restrict__ w,
                                             ushort_t* __restrict__ wt) {
  __shared__ float tile[32 * 33];
  int tx = threadIdx.x & 31, ty = threadIdx.x >> 5;
  int v0 = blockIdx.x * 32, k0 = blockIdx.y * 32;
  #pragma unroll
  for (int rr = 0; rr < 4; rr++) {
    int kk = ty * 4 + rr;
    int vv = v0 + tx;
    tile[kk * 33 + tx] = (vv < V_) ? w[(size_t)(k0 + kk) * V_ + vv] : 0.f;
  }
  __syncthreads();
  #pragma unroll
  for (int rr = 0; rr < 4; rr++) {
    int vv = ty * 4 + rr;
    wt[(size_t)(v0 + vv) * E_ + k0 + tx] = f2bf(tile[tx * 33 + vv]);
  }
}

// ---------------- vocab GEMM: 256v x 64s per block, two 128-v halves -------------
__global__ __launch_bounds__(256) void k_vocab(
    const ushort_t* __restrict__ hbf, const ushort_t* __restrict__ wt,
    const float* __restrict__ db2, float* __restrict__ out,
    float* __restrict__ pmax, float* __restrict__ psum) {
  __shared__ ushort_t hs[64 * 264];
  __shared__ float redm[4][64];
  __shared__ float reds[4][64];
  int n = blockIdx.x, vt = blockIdx.y;
  int tid = threadIdx.x, lane = tid & 63, wv = tid >> 6;
  const ushort_t* hsrc = hbf + (size_t)n * S_ * E_;
  for (int i = tid; i < (S_ * E_) / 8; i += 256) {
    int s = i >> 5, kc = (i & 31) * 8;
    *(uint4*)&hs[s * 264 + kc] = *(const uint4*)&hsrc[s * E_ + kc];
  }
  __syncthreads();
  int l15 = lane & 15, l4 = lane >> 4;
  float rm[4], rs[4];
  #pragma unroll
  for (int st = 0; st < 4; st++) { rm[st] = -INFINITY; rs[st] = 0.f; }
  #pragma unroll
  for (int h2 = 0; h2 < 2; h2++) {
    const ushort_t* Ap0 =
        wt + (size_t)(vt * 256 + h2 * 128 + wv * 16 + l15) * E_ + l4 * 8;
    const ushort_t* Ap1 = Ap0 + (size_t)64 * E_;
    f32x4 acc[2][4] = {};
    #pragma unroll
    for (int kb = 0; kb < 8; kb++) {
      bf16x8 a0 = *(const bf16x8*)(Ap0 + kb * 32);
      bf16x8 a1 = *(const bf16x8*)(Ap1 + kb * 32);
      #pragma unroll
      for (int st = 0; st < 4; st++) {
        bf16x8 bfr = *(const bf16x8*)&hs[(st * 16 + l15) * 264 + kb * 32 + l4 * 8];
        acc[0][st] = MFMA16(a0, bfr, acc[0][st]);
        acc[1][st] = MFMA16(a1, bfr, acc[1][st]);
      }
    }
    float vals[2][4][4];
    #pragma unroll
    for (int mt = 0; mt < 2; mt++) {
      #pragma unroll
      for (int j = 0; j < 4; j++) {
        int v = vt * 256 + h2 * 128 + wv * 16 + mt * 64 + l4 * 4 + j;
        bool valid = v < V_;
        float bias = valid ? db2[v] : 0.f;
        size_t ob = ((size_t)n * V_ + v) * S_;
        #pragma unroll
        for (int st = 0; st < 4; st++) {
          float val = valid ? (acc[mt][st][j] + bias) : -INFINITY;
          vals[mt][st][j] = val;
          if (valid) __builtin_nontemporal_store(val, &out[ob + st * 16 + l15]);
        }
      }
    }
    #pragma unroll
    for (int st = 0; st < 4; st++) {
      float m = -INFINITY;
      #pragma unroll
      for (int mt = 0; mt < 2; mt++)
        #pragma unroll
        for (int j = 0; j < 4; j++) m = fmaxf(m, vals[mt][st][j]);
      m = fmaxf(m, __shfl_xor(m, 16, 64));
      m = fmaxf(m, __shfl_xor(m, 32, 64));
      float sum = 0.f;
      #pragma unroll
      for (int mt = 0; mt < 2; mt++)
        #pragma unroll
        for (int j = 0; j < 4; j++) sum += __expf(vals[mt][st][j] - m);
      sum += __shfl_xor(sum, 16, 64);
      sum += __shfl_xor(sum, 32, 64);
      float nm = fmaxf(rm[st], m);
      rs[st] = rs[st] * __expf(rm[st] - nm) + sum * __expf(m - nm);
      rm[st] = nm;
    }
  }
  if (l4 == 0) {
    #pragma unroll
    for (int st = 0; st < 4; st++) {
      redm[wv][st * 16 + l15] = rm[st];
      reds[wv][st * 16 + l15] = rs[st];
    }
  }
  __syncthreads();
  if (wv == 0 && l4 == 0) {
    #pragma unroll
    for (int st = 0; st < 4; st++) {
      int s = st * 16 + l15;
      float M = fmaxf(fmaxf(redm[0][s], redm[1][s]), fmaxf(redm[2][s], redm[3][s]));
      float Sa = reds[0][s] * __expf(redm[0][s] - M) +
                 reds[1][s] * __expf(redm[1][s] - M) +
                 reds[2][s] * __expf(redm[2][s] - M) +
                 reds[3][s] * __expf(redm[3][s] - M);
      size_t pi = ((size_t)n * NVT_ + vt) * S_ + s;
      pmax[pi] = M;
      psum[pi] = Sa;
    }
  }
}

// ---------------- loss finalize (512 threads) ----------------
__global__ __launch_bounds__(512) void k_lossf(
    const float* __restrict__ pmax, const float* __restrict__ psum,
    const float* __restrict__ out, const int* __restrict__ label,
    float* __restrict__ partial) {
  __shared__ float sm[512], ssum[512];
  int n = blockIdx.x, tid = threadIdx.x;
  int s = tid & 63, qq = tid >> 6;  // qq in [0,8)
  float m = -INFINITY, sum = 0.f;
  for (int vt = qq; vt < NVT_; vt += 8) {
    size_t pi = ((size_t)n * NVT_ + vt) * S_ + s;
    float m2 = pmax[pi], s2 = psum[pi];
    float nm = fmaxf(m, m2);
    sum = sum * __expf(m - nm) + s2 * __expf(m2 - nm);
    m = nm;
  }
  sm[tid] = m; ssum[tid] = sum;
  __syncthreads();
  if (qq == 0) {
    float M = sm[s], Sa = ssum[s];
    #pragma unroll
    for (int p = 1; p < 8; p++) {
      float m2 = sm[p * 64 + s], s2 = ssum[p * 64 + s];
      float nm = fmaxf(M, m2);
      Sa = Sa * __expf(M - nm) + s2 * __expf(m2 - nm);
      M = nm;
    }
    float lse = M + logf(Sa);
    int lab = label[n * S_ + s];
    float lx = out[((size_t)n * V_ + lab) * S_ + s];
    partial[n * S_ + s] = lse - lx;
  }
}

__global__ __launch_bounds__(256) void k_loss2(const float* __restrict__ partial,
                                               float* __restrict__ dst) {
  __shared__ float sbuf[4];
  int tid = threadIdx.x;
  float acc = 0.f;
  for (int i = tid; i < T_; i += 256) acc += partial[i];
  #pragma unroll
  for (int off = 32; off >= 1; off >>= 1) acc += __shfl_xor(acc, off, 64);
  int lane = tid & 63, wid = tid >> 6;
  if (lane == 0) sbuf[wid] = acc;
  __syncthreads();
  if (tid == 0) dst[0] = (sbuf[0] + sbuf[1] + sbuf[2] + sbuf[3]) / (float)T_;
}

extern "C" void kernel_launch(void* const* d_in, const int* in_sizes, int n_in,
                              void* d_out, int out_size, void* d_ws, size_t ws_size,
                              hipStream_t stream) {
  const int*   label = (const int*)d_in[0];
  const int*   mask  = (const int*)d_in[1];
  const float* emb   = (const float*)d_in[2];
  const float* pos   = (const float*)d_in[3];
  const float* emb_g = (const float*)d_in[4];
  const float* emb_b = (const float*)d_in[5];
  const float* Wq  = (const float*)d_in[6];
  const float* bq  = (const float*)d_in[7];
  const float* Wk  = (const float*)d_in[8];
  const float* bk  = (const float*)d_in[9];
  const float* Wv  = (const float*)d_in[10];
  const float* bv  = (const float*)d_in[11];
  const float* Wo  = (const float*)d_in[12];
  const float* bo  = (const float*)d_in[13];
  const float* n1g = (const float*)d_in[14];
  const float* n1b = (const float*)d_in[15];
  const float* W1  = (const float*)d_in[16];
  const float* b1  = (const float*)d_in[17];
  const float* W2  = (const float*)d_in[18];
  const float* b2  = (const float*)d_in[19];
  const float* n2g = (const float*)d_in[20];
  const float* n2b = (const float*)d_in[21];
  const float* dW1 = (const float*)d_in[22];
  const float* db1 = (const float*)d_in[23];
  const float* dng = (const float*)d_in[24];
  const float* dnb = (const float*)d_in[25];
  const float* dW2 = (const float*)d_in[26];
  const float* db2 = (const float*)d_in[27];
  float* out = (float*)d_out;
  (void)in_sizes; (void)n_in; (void)out_size; (void)ws_size;

  char* base = (char*)d_ws;
  size_t off = 0;
  auto alloc = [&](size_t bytes) {
    char* p = base + off;
    off += (bytes + 255) & ~(size_t)255;
    return p;
  };
  float*    x    = (float*)alloc((size_t)T_ * E_ * 4);
  ushort_t* xb   = (ushort_t*)alloc((size_t)T_ * E_ * 2);
  ushort_t* obuf = (ushort_t*)alloc((size_t)T_ * E_ * 2);
  ushort_t* wqkvT = (ushort_t*)alloc((size_t)L_ * 768 * E_ * 2);
  ushort_t* woT   = (ushort_t*)alloc((size_t)L_ * E_ * E_ * 2);
  ushort_t* w1T   = (ushort_t*)alloc((size_t)L_ * H_ * E_ * 2);
  ushort_t* w2T   = (ushort_t*)alloc((size_t)L_ * E_ * H_ * 2);
  ushort_t* dw1T  = (ushort_t*)alloc((size_t)E_ * E_ * 2);
  ushort_t* wt    = (ushort_t*)alloc((size_t)VPAD_ * E_ * 2);
  float*    bqkv  = (float*)alloc((size_t)L_ * 768 * 4);
  float*    partial = (float*)alloc((size_t)T_ * 4);
  ushort_t* hbf = obuf;       // alias: obuf dead after the loop
  float* pmax = x;            // alias: x dead by k_vocab (~8.6 MB needed)
  float* psum = pmax + (size_t)N_ * NVT_ * S_;

  // ---- one-time weight prep (2 launches) ----
  k_prep<<<dim3(16, 16, 26), 256, 0, stream>>>(Wq, Wk, Wv, Wo, dW1, W1, W2,
                                               bq, bk, bv, wqkvT, woT, dw1T,
                                               w1T, w2T, bqkv);
  k_w2t<<<dim3(VPAD_ / 32, E_ / 32), 256, 0, stream>>>(dW2, wt);

  k_embed_ln<<<T_ / 4, 256, 0, stream>>>(label, mask, emb, pos, emb_g, emb_b, x, xb);

  for (int l = 0; l < L_; l++) {
    // fused QKV + attention -> obuf (bf16)
    k_qa<<<N_ * NH_, 256, 0, stream>>>(
        xb, wqkvT + (size_t)l * 768 * E_, bqkv + l * 768, obuf);
    // fused Wo + res + LN1 + FFN + res + LN2 -> x (f32, skipped on last) + xb
    k_aof<<<T_ / 16, 256, 0, stream>>>(
        obuf, woT + (size_t)l * E_ * E_, bo + l * E_, x,
        n1g + l * E_, n1b + l * E_,
        w1T + (size_t)l * H_ * E_, b1 + l * H_,
        w2T + (size_t)l * E_ * H_, b2 + l * E_,
        n2g + l * E_, n2b + l * E_,
        (l == L_ - 1) ? nullptr : x, xb);
  }

  // decoder head: LN(gelu(x @ dW1 + db1)) -> hbf (bf16)
  k_mm_ln2<E_, 1><<<T_ / 16, 256, 0, stream>>>(xb, dw1T, db1, dng, dnb, hbf);

  // vocab projection + transposed store + fused softmax partials
  k_vocab<<<dim3(N_, NVT_), 256, 0, stream>>>(hbf, wt, db2, out, pmax, psum);

  // loss
  k_lossf<<<N_, 512, 0, stream>>>(pmax, psum, out, label, partial);
  k_loss2<<<1, 256, 0, stream>>>(partial, out + (size_t)N_ * V_ * S_);
}